// Round 7
// baseline (601.390 us; speedup 1.0000x reference)
//
#include <hip/hip_runtime.h>
#include <math.h>

#define SEQ 512
#define HID 768
#define NBATCH 16
#define ROWS 8192
#define INV_SQRT_D 0.07216878364870323f

typedef short s8v __attribute__((ext_vector_type(8)));
typedef float f4v __attribute__((ext_vector_type(4)));
typedef unsigned short u16;

// ---- bf16 helpers (RNE) ----
__device__ __forceinline__ u16 f2bf(float f) {
  unsigned u = __builtin_bit_cast(unsigned, f);
  unsigned r = u + 0x7FFFu + ((u >> 16) & 1u);
  return (u16)(r >> 16);
}
__device__ __forceinline__ float bf2f(u16 s) {
  unsigned u = ((unsigned)s) << 16;
  return __builtin_bit_cast(float, u);
}

// ---------------------------------------------------------------------------
// LDS-free GEMM core: MFMA fragments loaded DIRECTLY from global (L1/L2).
// Both operands are k-contiguous; frag addr = (tile_row + ml)*ld + ks*32 + quad*8
// -> per 4 lanes one contiguous 64B segment (coalesced), L2-resident panels.
// No LDS, no barriers: waves self-pace on vmcnt; 3 waves/SIMD hide L2 latency.
// acc += Ah*Bh + Ah*Bl + Al*Bh per K=32 step (split-bf16 precision scheme).
// ---------------------------------------------------------------------------
template <int KSTEPS, int MI, int NJ>
__device__ __forceinline__ void mm_direct(
    const u16* __restrict__ Ah, const u16* __restrict__ Al, const int lda, const int mrow,
    const u16* __restrict__ Bh, const u16* __restrict__ Bl, const int ldb, const int ncol,
    f4v (&acc)[MI][NJ])
{
  const int ln = threadIdx.x & 63;
  const int ml = ln & 15, quad = ln >> 4;
  int oa[MI], ob[NJ];
#pragma unroll
  for (int i = 0; i < MI; ++i) oa[i] = (mrow + i * 16 + ml) * lda + quad * 8;
#pragma unroll
  for (int j = 0; j < NJ; ++j) ob[j] = (ncol + j * 16 + ml) * ldb + quad * 8;

  for (int ks = 0; ks < KSTEPS; ++ks) {
    const int k0 = ks * 32;
    s8v ah[MI], al[MI], bh[NJ], bl[NJ];
#pragma unroll
    for (int i = 0; i < MI; ++i) {
      ah[i] = *(const s8v*)(Ah + oa[i] + k0);
      al[i] = *(const s8v*)(Al + oa[i] + k0);
    }
#pragma unroll
    for (int j = 0; j < NJ; ++j) {
      bh[j] = *(const s8v*)(Bh + ob[j] + k0);
      bl[j] = *(const s8v*)(Bl + ob[j] + k0);
    }
#pragma unroll
    for (int i = 0; i < MI; ++i)
#pragma unroll
      for (int j = 0; j < NJ; ++j)
        acc[i][j] = __builtin_amdgcn_mfma_f32_16x16x32_bf16(ah[i], bh[j], acc[i][j], 0, 0, 0);
#pragma unroll
    for (int i = 0; i < MI; ++i)
#pragma unroll
      for (int j = 0; j < NJ; ++j)
        acc[i][j] = __builtin_amdgcn_mfma_f32_16x16x32_bf16(ah[i], bl[j], acc[i][j], 0, 0, 0);
#pragma unroll
    for (int i = 0; i < MI; ++i)
#pragma unroll
      for (int j = 0; j < NJ; ++j)
        acc[i][j] = __builtin_amdgcn_mfma_f32_16x16x32_bf16(al[i], bh[j], acc[i][j], 0, 0, 0);
  }
}

// ---- prep: split x into hi/lo bf16 ----
__global__ __launch_bounds__(256) void splitx(const float* __restrict__ x,
                                              u16* __restrict__ xh, u16* __restrict__ xl)
{
  const int i = blockIdx.x * 256 + threadIdx.x;
  const float4 v = ((const float4*)x)[i];
  u16 h0 = f2bf(v.x), h1 = f2bf(v.y), h2 = f2bf(v.z), h3 = f2bf(v.w);
  ushort4 hv = make_ushort4(h0, h1, h2, h3);
  ushort4 lv = make_ushort4(f2bf(v.x - bf2f(h0)), f2bf(v.y - bf2f(h1)),
                            f2bf(v.z - bf2f(h2)), f2bf(v.w - bf2f(h3)));
  ((ushort4*)xh)[i] = hv;
  ((ushort4*)xl)[i] = lv;
}

// ---- prep: transpose + split weights: WT[z][n][k] = W_z[k][n] ----
__global__ __launch_bounds__(256) void wsplit(
    const float* __restrict__ Wq, const float* __restrict__ Wk,
    const float* __restrict__ Wv, const float* __restrict__ Wo,
    u16* __restrict__ WTh, u16* __restrict__ WTl)
{
  __shared__ float t[32][33];
  const int z = blockIdx.z;
  const float* W = (z == 0) ? Wq : (z == 1) ? Wk : (z == 2) ? Wv : Wo;
  const int n0 = blockIdx.x * 32, k0 = blockIdx.y * 32;
  const int tx = threadIdx.x & 31, ty = threadIdx.x >> 5;
#pragma unroll
  for (int i = 0; i < 4; ++i)
    t[ty + 8 * i][tx] = W[(size_t)(k0 + ty + 8 * i) * HID + n0 + tx];
  __syncthreads();
#pragma unroll
  for (int i = 0; i < 4; ++i) {
    const float v = t[tx][ty + 8 * i];
    const size_t idx = (size_t)z * HID * HID + (size_t)(n0 + ty + 8 * i) * HID + k0 + tx;
    const u16 hi = f2bf(v);
    WTh[idx] = hi;
    WTl[idx] = f2bf(v - bf2f(hi));
  }
}

// ---- QKV GEMM, XCD-swizzled 1D grid (1152 blocks), LDS-free core ----
__global__ __launch_bounds__(256, 3) void qkv_mm(
    const u16* __restrict__ xh, const u16* __restrict__ xl,
    const u16* __restrict__ WTh, const u16* __restrict__ WTl,
    const float* __restrict__ bq, const float* __restrict__ bk, const float* __restrict__ bv,
    u16* __restrict__ qh, u16* __restrict__ ql,
    u16* __restrict__ kh, u16* __restrict__ kl, float* __restrict__ vtmp)
{
  const int id = blockIdx.x;
  const int xcd = id & 7;
  const int s = id >> 3;            // 0..143
  const int bx = s % 6;
  const int yl = (s / 6) & 7;
  const int z  = s / 48;
  const int bm = (yl * 8 + xcd) * 128;
  const int bn = bx * 128;
  const int tid = threadIdx.x, w = tid >> 6, ln = tid & 63;
  const int wr = (w >> 1) * 64, wc = (w & 1) * 64;
  f4v acc[4][4];
#pragma unroll
  for (int i = 0; i < 4; ++i)
#pragma unroll
    for (int j = 0; j < 4; ++j) acc[i][j] = (f4v)0.f;
  const u16* Bh = WTh + (size_t)z * HID * HID;
  const u16* Bl = WTl + (size_t)z * HID * HID;
  mm_direct<24, 4, 4>(xh, xl, HID, bm + wr, Bh, Bl, HID, bn + wc, acc);

  const int ml = ln & 15, quad = ln >> 4;
  const float* bias = (z == 0) ? bq : (z == 1) ? bk : bv;
#pragma unroll
  for (int i = 0; i < 4; ++i)
#pragma unroll
    for (int j = 0; j < 4; ++j) {
      const int gcol = bn + wc + j * 16 + ml;
      const float bv_ = bias[gcol];
#pragma unroll
      for (int r = 0; r < 4; ++r) {
        const int grow = bm + wr + i * 16 + quad * 4 + r;
        const float v = acc[i][j][r] + bv_;
        const size_t idx = (size_t)grow * HID + gcol;
        if (z == 2) {
          vtmp[idx] = v;
        } else {
          const u16 hi = f2bf(v);
          const u16 lo = f2bf(v - bf2f(hi));
          if (z == 0) { qh[idx] = hi; ql[idx] = lo; }
          else        { kh[idx] = hi; kl[idx] = lo; }
        }
      }
    }
}

// ---- prep: transpose + split v: vT[b][n][c] = vtmp[b][c][n] ----
__global__ __launch_bounds__(256) void vtrans(const float* __restrict__ vtmp,
                                              u16* __restrict__ vTh, u16* __restrict__ vTl)
{
  __shared__ float t[32][33];
  const int b = blockIdx.z, n0 = blockIdx.x * 32, c0 = blockIdx.y * 32;
  const int tx = threadIdx.x & 31, ty = threadIdx.x >> 5;
  const float* src = vtmp + (size_t)b * SEQ * HID;
#pragma unroll
  for (int i = 0; i < 4; ++i)
    t[ty + 8 * i][tx] = src[(size_t)(c0 + ty + 8 * i) * HID + n0 + tx];
  __syncthreads();
#pragma unroll
  for (int i = 0; i < 4; ++i) {
    const float v = t[tx][ty + 8 * i];
    const size_t idx = (size_t)b * HID * SEQ + (size_t)(n0 + ty + 8 * i) * SEQ + c0 + tx;
    const u16 hi = f2bf(v);
    vTh[idx] = hi;
    vTl[idx] = f2bf(v - bf2f(hi));
  }
}

// ---- scores GEMM + fused rel-bias/scale/dist-mask epilogue (fp32 out) ----
__global__ __launch_bounds__(256, 3) void scores_mm(
    const u16* __restrict__ qh, const u16* __restrict__ ql,
    const u16* __restrict__ kh, const u16* __restrict__ kl, float* __restrict__ sc)
{
  const int z = blockIdx.z, b = z >> 2, hh = z & 3;
  const int bm = blockIdx.y * 128, bn = blockIdx.x * 128;
  const int tid = threadIdx.x, w = tid >> 6, ln = tid & 63;
  const int wr = (w >> 1) * 64, wc = (w & 1) * 64;
  const size_t base = (size_t)(b * SEQ) * HID + hh * 192;
  f4v acc[4][4];
#pragma unroll
  for (int i = 0; i < 4; ++i)
#pragma unroll
    for (int j = 0; j < 4; ++j) acc[i][j] = (f4v)0.f;
  mm_direct<6, 4, 4>(qh + base, ql + base, HID, bm + wr,
                     kh + base, kl + base, HID, bn + wc, acc);
  const int ml = ln & 15, quad = ln >> 4;
  float* sch = sc + (size_t)z * SEQ * SEQ;
#pragma unroll
  for (int i = 0; i < 4; ++i)
#pragma unroll
    for (int j = 0; j < 4; ++j) {
      const int scol = bn + wc + j * 16 + ml;
#pragma unroll
      for (int r = 0; r < 4; ++r) {
        const int srow = bm + wr + i * 16 + quad * 4 + r;
        const float dist = fabsf((float)(srow - scol));
        const float rel = __expf(-0.1f * fminf(dist, 5.0f));
        sch[(size_t)srow * SEQ + scol] =
            (acc[i][j][r] + rel) * INV_SQRT_D - 0.1f * dist;
      }
    }
}

// ---- softmax in-place, writes probs hi/lo bf16 into the same row bytes ----
__global__ __launch_bounds__(256) void softmax_split(float* __restrict__ sc)
{
  const int blk = blockIdx.x;
  const int z = blk >> 7, rg = blk & 127;
  const int tid = threadIdx.x;
  const int rr = tid >> 6, lane = tid & 63;
  const int r = rg * 4 + rr;
  float* row = sc + (size_t)z * SEQ * SEQ + (size_t)r * SEQ;
  float4 v0 = *(const float4*)(row + lane * 8);
  float4 v1 = *(const float4*)(row + lane * 8 + 4);
  float mx = fmaxf(fmaxf(fmaxf(v0.x, v0.y), fmaxf(v0.z, v0.w)),
                   fmaxf(fmaxf(v1.x, v1.y), fmaxf(v1.z, v1.w)));
#pragma unroll
  for (int o = 32; o > 0; o >>= 1) mx = fmaxf(mx, __shfl_xor(mx, o, 64));
  v0.x = __expf(v0.x - mx); v0.y = __expf(v0.y - mx);
  v0.z = __expf(v0.z - mx); v0.w = __expf(v0.w - mx);
  v1.x = __expf(v1.x - mx); v1.y = __expf(v1.y - mx);
  v1.z = __expf(v1.z - mx); v1.w = __expf(v1.w - mx);
  float s = v0.x + v0.y + v0.z + v0.w + v1.x + v1.y + v1.z + v1.w;
#pragma unroll
  for (int o = 32; o > 0; o >>= 1) s += __shfl_xor(s, o, 64);
  const float inv = 1.0f / s;
  float p[8] = {v0.x * inv, v0.y * inv, v0.z * inv, v0.w * inv,
                v1.x * inv, v1.y * inv, v1.z * inv, v1.w * inv};
  u16 hi[8], lo[8];
#pragma unroll
  for (int t = 0; t < 8; ++t) {
    hi[t] = f2bf(p[t]);
    lo[t] = f2bf(p[t] - bf2f(hi[t]));
  }
  u16* ph = (u16*)row;                       // [0,512) hi, [512,1024) lo
  ushort4* d0 = (ushort4*)&ph[lane * 8];
  d0[0] = make_ushort4(hi[0], hi[1], hi[2], hi[3]);
  d0[1] = make_ushort4(hi[4], hi[5], hi[6], hi[7]);
  ushort4* d1 = (ushort4*)&ph[512 + lane * 8];
  d1[0] = make_ushort4(lo[0], lo[1], lo[2], lo[3]);
  d1[1] = make_ushort4(lo[4], lo[5], lo[6], lo[7]);
}

// ---- PV GEMM: block = 64(M) x 192(N), wave = 64x48 strip, LDS-free ----
__global__ __launch_bounds__(256, 3) void pv_mm(
    const u16* __restrict__ pbase, const u16* __restrict__ vTh, const u16* __restrict__ vTl,
    u16* __restrict__ ch, u16* __restrict__ cl)
{
  const int z = blockIdx.y, b = z >> 2, hh = z & 3;
  const int bm = blockIdx.x * 64;
  const int tid = threadIdx.x, w = tid >> 6, ln = tid & 63;
  const u16* Ah = pbase + (size_t)z * SEQ * 1024;      // probs hi, ld 1024
  const u16* Al = Ah + 512;                            // probs lo
  const u16* Bh = vTh + (size_t)b * HID * SEQ + (size_t)(hh * 192) * SEQ;  // ld 512
  const u16* Bl = vTl + (size_t)b * HID * SEQ + (size_t)(hh * 192) * SEQ;
  f4v acc[4][3];
#pragma unroll
  for (int i = 0; i < 4; ++i)
#pragma unroll
    for (int j = 0; j < 3; ++j) acc[i][j] = (f4v)0.f;
  mm_direct<16, 4, 3>(Ah, Al, 1024, bm, Bh, Bl, SEQ, w * 48, acc);

  const int ml = ln & 15, quad = ln >> 4;
#pragma unroll
  for (int i = 0; i < 4; ++i)
#pragma unroll
    for (int j = 0; j < 3; ++j) {
      const int gcol = hh * 192 + w * 48 + j * 16 + ml;
#pragma unroll
      for (int r = 0; r < 4; ++r) {
        const int m = bm + i * 16 + quad * 4 + r;
        const float v = acc[i][j][r];
        const size_t idx = (size_t)(b * SEQ + m) * HID + gcol;
        const u16 hi = f2bf(v);
        ch[idx] = hi;
        cl[idx] = f2bf(v - bf2f(hi));
      }
    }
}

// ---- projection GEMM + bias + residual -> h fp32 (XCD-swizzled, LDS-free) ----
__global__ __launch_bounds__(256, 3) void proj_mm(
    const u16* __restrict__ ch, const u16* __restrict__ cl,
    const u16* __restrict__ WTh, const u16* __restrict__ WTl,
    const float* __restrict__ bo, const float* __restrict__ x, float* __restrict__ h)
{
  const int id = blockIdx.x;
  const int xcd = id & 7;
  const int s = id >> 3;            // 0..47
  const int bx = s % 6;
  const int yl = s / 6;             // 0..7
  const int bm = (yl * 8 + xcd) * 128;
  const int bn = bx * 128;
  const int tid = threadIdx.x, w = tid >> 6, ln = tid & 63;
  const int wr = (w >> 1) * 64, wc = (w & 1) * 64;
  const u16* Bh = WTh + (size_t)3 * HID * HID;
  const u16* Bl = WTl + (size_t)3 * HID * HID;
  f4v acc[4][4];
#pragma unroll
  for (int i = 0; i < 4; ++i)
#pragma unroll
    for (int j = 0; j < 4; ++j) acc[i][j] = (f4v)0.f;
  mm_direct<24, 4, 4>(ch, cl, HID, bm + wr, Bh, Bl, HID, bn + wc, acc);

  const int ml = ln & 15, quad = ln >> 4;
#pragma unroll
  for (int i = 0; i < 4; ++i)
#pragma unroll
    for (int j = 0; j < 4; ++j) {
      const int gcol = bn + wc + j * 16 + ml;
      const float bv_ = bo[gcol];
#pragma unroll
      for (int r = 0; r < 4; ++r) {
        const int grow = bm + wr + i * 16 + quad * 4 + r;
        const size_t idx = (size_t)grow * HID + gcol;
        h[idx] = acc[i][j][r] + bv_ + x[idx];
      }
    }
}

// ---- LayerNorm + 9-label classifier ----
__global__ __launch_bounds__(256) void ln_logits_kernel(
    const float* __restrict__ h, const float* __restrict__ g,
    const float* __restrict__ bta, const float* __restrict__ Ws,
    const float* __restrict__ bsv, float* __restrict__ span)
{
  const int row = blockIdx.x;
  const int tid = threadIdx.x;
  const float* hr = h + (size_t)row * HID;
  const float x0 = hr[tid], x1 = hr[tid + 256], x2 = hr[tid + 512];
  float s = x0 + x1 + x2;
  float sq = x0 * x0 + x1 * x1 + x2 * x2;
#pragma unroll
  for (int o = 32; o > 0; o >>= 1) { s += __shfl_down(s, o, 64); sq += __shfl_down(sq, o, 64); }
  __shared__ float red[8];
  __shared__ float smu, srs;
  const int wid = tid >> 6, lid = tid & 63;
  if (lid == 0) { red[wid] = s; red[4 + wid] = sq; }
  __syncthreads();
  if (tid == 0) {
    const float ts = red[0] + red[1] + red[2] + red[3];
    const float tq = red[4] + red[5] + red[6] + red[7];
    const float mu = ts / 768.0f;
    const float var = tq / 768.0f - mu * mu;
    smu = mu; srs = rsqrtf(var + 1e-5f);
  }
  __syncthreads();
  const float mu = smu, rs = srs;
  const float n0 = (x0 - mu) * rs * g[tid] + bta[tid];
  const float n1 = (x1 - mu) * rs * g[tid + 256] + bta[tid + 256];
  const float n2 = (x2 - mu) * rs * g[tid + 512] + bta[tid + 512];
  float pl[9];
#pragma unroll
  for (int l = 0; l < 9; ++l)
    pl[l] = n0 * Ws[(size_t)tid * 9 + l]
          + n1 * Ws[(size_t)(tid + 256) * 9 + l]
          + n2 * Ws[(size_t)(tid + 512) * 9 + l];
#pragma unroll
  for (int l = 0; l < 9; ++l)
#pragma unroll
    for (int o = 32; o > 0; o >>= 1) pl[l] += __shfl_down(pl[l], o, 64);
  __shared__ float lred[4][9];
  if (lid == 0) {
#pragma unroll
    for (int l = 0; l < 9; ++l) lred[wid][l] = pl[l];
  }
  __syncthreads();
  if (tid < 9) {
    span[(size_t)row * 9 + tid] =
        lred[0][tid] + lred[1][tid] + lred[2][tid] + lred[3][tid] + bsv[tid];
  }
}

// ---- entity-bias bump ----
__global__ __launch_bounds__(256) void bump_kernel(
    const float* __restrict__ span, const float* __restrict__ eb, float* __restrict__ out)
{
  const int idx = blockIdx.x * 256 + threadIdx.x;
  if (idx >= ROWS) return;
  const int j = idx & (SEQ - 1);
  const float* sl = span + (size_t)idx * 9;
  float v[9];
#pragma unroll
  for (int l = 0; l < 9; ++l) v[l] = sl[l];
  if (j >= 1) {
    const float* sp = sl - 9;
    float m = sp[0]; int am = 0;
#pragma unroll
    for (int l = 1; l < 9; ++l) { const float t = sp[l]; if (t > m) { m = t; am = l; } }
    if (am == 1) v[2] += 2.0f * eb[2];
  }
#pragma unroll
  for (int l = 0; l < 9; ++l) out[(size_t)idx * 9 + l] = v[l];
}

extern "C" void kernel_launch(void* const* d_in, const int* in_sizes, int n_in,
                              void* d_out, int out_size, void* d_ws, size_t ws_size,
                              hipStream_t stream)
{
  (void)in_sizes; (void)n_in; (void)out_size; (void)ws_size;
  const float* x   = (const float*)d_in[0];
  const float* Wq  = (const float*)d_in[1];
  const float* bq  = (const float*)d_in[2];
  const float* Wk  = (const float*)d_in[3];
  const float* bk  = (const float*)d_in[4];
  const float* Wv  = (const float*)d_in[5];
  const float* bv  = (const float*)d_in[6];
  const float* Wo  = (const float*)d_in[7];
  const float* bo  = (const float*)d_in[8];
  const float* lng = (const float*)d_in[9];
  const float* lnb = (const float*)d_in[10];
  const float* Ws  = (const float*)d_in[11];
  const float* bs  = (const float*)d_in[12];
  const float* eb  = (const float*)d_in[13];
  float* out = (float*)d_out;

  char* ws = (char*)d_ws;
  u16* xh  = (u16*)(ws + 0);
  u16* xl  = (u16*)(ws + 12582912);
  u16* vTh = xh;
  u16* vTl = xl;
  u16* WTh = (u16*)(ws + 25165824);
  u16* WTl = (u16*)(ws + 29884416);
  u16* qh  = (u16*)(ws + 34603008);
  u16* ql  = (u16*)(ws + 47185920);
  u16* kh  = (u16*)(ws + 59768832);
  u16* kl  = (u16*)(ws + 72351744);
  float* scb = (float*)(ws + 84934656);
  float* spanb = (float*)(ws + 152043520);
  float* vtmp = scb;
  float* hb = scb;
  u16* ctxh = qh;
  u16* ctxl = ql;

  splitx<<<dim3(1572864 / 256), 256, 0, stream>>>(x, xh, xl);
  wsplit<<<dim3(24, 24, 4), 256, 0, stream>>>(Wq, Wk, Wv, Wo, WTh, WTl);
  qkv_mm<<<dim3(1152), 256, 0, stream>>>(xh, xl, WTh, WTl, bq, bk, bv,
                                         qh, ql, kh, kl, vtmp);
  vtrans<<<dim3(24, 16, 16), 256, 0, stream>>>(vtmp, vTh, vTl);
  scores_mm<<<dim3(4, 4, 64), 256, 0, stream>>>(qh, ql, kh, kl, scb);
  softmax_split<<<dim3(8192), 256, 0, stream>>>(scb);
  pv_mm<<<dim3(8, 64), 256, 0, stream>>>((const u16*)scb, vTh, vTl, ctxh, ctxl);
  proj_mm<<<dim3(384), 256, 0, stream>>>(ctxh, ctxl, WTh, WTl, bo, x, hb);
  ln_logits_kernel<<<dim3(ROWS), 256, 0, stream>>>(hb, lng, lnb, Ws, bs, spanb);
  bump_kernel<<<dim3(ROWS / 256), 256, 0, stream>>>(spanb, eb, out);
}

// Round 8
// 390.154 us; speedup vs baseline: 1.5414x; 1.5414x over previous
//
#include <hip/hip_runtime.h>
#include <math.h>

#define SEQ 512
#define HID 768
#define NBATCH 16
#define ROWS 8192
#define INV_SQRT_D 0.07216878364870323f

typedef short s8v __attribute__((ext_vector_type(8)));
typedef float f4v __attribute__((ext_vector_type(4)));
typedef unsigned short u16;

// ---- bf16 helpers (RNE) ----
__device__ __forceinline__ u16 f2bf(float f) {
  unsigned u = __builtin_bit_cast(unsigned, f);
  unsigned r = u + 0x7FFFu + ((u >> 16) & 1u);
  return (u16)(r >> 16);
}
__device__ __forceinline__ float bf2f(u16 s) {
  unsigned u = ((unsigned)s) << 16;
  return __builtin_bit_cast(float, u);
}

// ---------------------------------------------------------------------------
// GEMM core v3: VGPR prefetch (depth 2) + LDS DOUBLE BUFFER, ONE barrier/kstep.
// Step ks: write regs(ks+1) into buf^1 (previous barrier guarantees its readers
// finished), issue global loads for ks+2, frag-read buf + 48 MFMA, barrier.
// LDS tile swizzle: (row,chunk) at row*32+((chunk+(row>>1))&3)*8 -> conflict-free
// b128 reads; ds_writes contiguous. Buffers: lds[0..16384) and [16384..32768).
// ---------------------------------------------------------------------------
template <int KSTEPS>
__device__ __forceinline__ void mm_core128(
    const u16* __restrict__ Ah, const u16* __restrict__ Al, const int lda,
    const u16* __restrict__ Bh, const u16* __restrict__ Bl, const int ldb,
    u16* lds, f4v (&acc)[4][4])
{
  const int tid = threadIdx.x;
  const int w = tid >> 6, ln = tid & 63;
  const u16* src; int ld;
  if (w == 0)      { src = Ah; ld = lda; }
  else if (w == 1) { src = Al; ld = lda; }
  else if (w == 2) { src = Bh; ld = ldb; }
  else             { src = Bl; ld = ldb; }
  const int srow = ln >> 2;
  const int csw  = ((ln & 3) - (ln >> 3)) & 3;
  const int ml = ln & 15, quad = ln >> 4;
  const int fo2 = (((ln >> 4) + ((ln >> 1) & 3)) & 3) * 8;
  const int wr = (w >> 1) * 64, wc = (w & 1) * 64;

  const u16* gp[8];
  int lpo[8];                          // write offsets within a buffer
#pragma unroll
  for (int t = 0; t < 8; ++t) {
    gp[t]  = src + (size_t)(srow + t * 16) * ld + csw * 8;
    lpo[t] = w * 4096 + t * 512 + ln * 8;
  }
  s8v c[8];
  // prologue: stage step 0 into buf0, prefetch step 1
#pragma unroll
  for (int t = 0; t < 8; ++t) c[t] = *(const s8v*)gp[t];
#pragma unroll
  for (int t = 0; t < 8; ++t) *(s8v*)&lds[lpo[t]] = c[t];
  if (KSTEPS > 1) {
#pragma unroll
    for (int t = 0; t < 8; ++t) c[t] = *(const s8v*)(gp[t] + 32);
  }
  __syncthreads();

  for (int ks = 0; ks < KSTEPS; ++ks) {
    u16* cur = lds + (ks & 1) * 16384;
    if (ks + 1 < KSTEPS) {
      u16* nxt = lds + ((ks + 1) & 1) * 16384;
#pragma unroll
      for (int t = 0; t < 8; ++t) *(s8v*)&nxt[lpo[t]] = c[t];
    }
    if (ks + 2 < KSTEPS) {
      const int k0 = (ks + 2) * 32;
#pragma unroll
      for (int t = 0; t < 8; ++t) c[t] = *(const s8v*)(gp[t] + k0);
    }
    s8v ah[4], al[4], bh[4], bl[4];
#pragma unroll
    for (int i = 0; i < 4; ++i) {
      const int ra = (wr + i * 16 + ml) * 32 + fo2;
      ah[i] = *(const s8v*)&cur[ra];
      al[i] = *(const s8v*)&cur[4096 + ra];
      const int rb = (wc + i * 16 + ml) * 32 + fo2;
      bh[i] = *(const s8v*)&cur[8192 + rb];
      bl[i] = *(const s8v*)&cur[12288 + rb];
    }
#pragma unroll
    for (int i = 0; i < 4; ++i)
#pragma unroll
      for (int j = 0; j < 4; ++j)
        acc[i][j] = __builtin_amdgcn_mfma_f32_16x16x32_bf16(ah[i], bh[j], acc[i][j], 0, 0, 0);
#pragma unroll
    for (int i = 0; i < 4; ++i)
#pragma unroll
      for (int j = 0; j < 4; ++j)
        acc[i][j] = __builtin_amdgcn_mfma_f32_16x16x32_bf16(ah[i], bl[j], acc[i][j], 0, 0, 0);
#pragma unroll
    for (int i = 0; i < 4; ++i)
#pragma unroll
      for (int j = 0; j < 4; ++j)
        acc[i][j] = __builtin_amdgcn_mfma_f32_16x16x32_bf16(al[i], bh[j], acc[i][j], 0, 0, 0);
    __syncthreads();
  }
}

// ---- prep: split x into hi/lo bf16 ----
__global__ __launch_bounds__(256) void splitx(const float* __restrict__ x,
                                              u16* __restrict__ xh, u16* __restrict__ xl)
{
  const int i = blockIdx.x * 256 + threadIdx.x;
  const float4 v = ((const float4*)x)[i];
  u16 h0 = f2bf(v.x), h1 = f2bf(v.y), h2 = f2bf(v.z), h3 = f2bf(v.w);
  ushort4 hv = make_ushort4(h0, h1, h2, h3);
  ushort4 lv = make_ushort4(f2bf(v.x - bf2f(h0)), f2bf(v.y - bf2f(h1)),
                            f2bf(v.z - bf2f(h2)), f2bf(v.w - bf2f(h3)));
  ((ushort4*)xh)[i] = hv;
  ((ushort4*)xl)[i] = lv;
}

// ---- prep: transpose + split weights: WT[z][n][k] = W_z[k][n] ----
__global__ __launch_bounds__(256) void wsplit(
    const float* __restrict__ Wq, const float* __restrict__ Wk,
    const float* __restrict__ Wv, const float* __restrict__ Wo,
    u16* __restrict__ WTh, u16* __restrict__ WTl)
{
  __shared__ float t[32][33];
  const int z = blockIdx.z;
  const float* W = (z == 0) ? Wq : (z == 1) ? Wk : (z == 2) ? Wv : Wo;
  const int n0 = blockIdx.x * 32, k0 = blockIdx.y * 32;
  const int tx = threadIdx.x & 31, ty = threadIdx.x >> 5;
#pragma unroll
  for (int i = 0; i < 4; ++i)
    t[ty + 8 * i][tx] = W[(size_t)(k0 + ty + 8 * i) * HID + n0 + tx];
  __syncthreads();
#pragma unroll
  for (int i = 0; i < 4; ++i) {
    const float v = t[tx][ty + 8 * i];
    const size_t idx = (size_t)z * HID * HID + (size_t)(n0 + ty + 8 * i) * HID + k0 + tx;
    const u16 hi = f2bf(v);
    WTh[idx] = hi;
    WTl[idx] = f2bf(v - bf2f(hi));
  }
}

// ---- QKV GEMM, XCD-swizzled 1D grid (1152 blocks), dbuf core ----
__global__ __launch_bounds__(256, 2) void qkv_mm(
    const u16* __restrict__ xh, const u16* __restrict__ xl,
    const u16* __restrict__ WTh, const u16* __restrict__ WTl,
    const float* __restrict__ bq, const float* __restrict__ bk, const float* __restrict__ bv,
    u16* __restrict__ qh, u16* __restrict__ ql,
    u16* __restrict__ kh, u16* __restrict__ kl, float* __restrict__ vtmp)
{
  __shared__ u16 lds[32768];
  const int id = blockIdx.x;
  const int xcd = id & 7;
  const int s = id >> 3;            // 0..143
  const int bx = s % 6;
  const int yl = (s / 6) & 7;
  const int z  = s / 48;
  const int bm = (yl * 8 + xcd) * 128;
  const int bn = bx * 128;
  const size_t wtoff = (size_t)z * HID * HID + (size_t)bn * HID;
  f4v acc[4][4];
#pragma unroll
  for (int i = 0; i < 4; ++i)
#pragma unroll
    for (int j = 0; j < 4; ++j) acc[i][j] = (f4v)0.f;
  mm_core128<24>(xh + (size_t)bm * HID, xl + (size_t)bm * HID, HID,
                 WTh + wtoff, WTl + wtoff, HID, lds, acc);
  const int tid = threadIdx.x, w = tid >> 6, ln = tid & 63;
  const int ml = ln & 15, quad = ln >> 4;
  const int wr = (w >> 1) * 64, wc = (w & 1) * 64;
  const float* bias = (z == 0) ? bq : (z == 1) ? bk : bv;
#pragma unroll
  for (int i = 0; i < 4; ++i)
#pragma unroll
    for (int j = 0; j < 4; ++j) {
      const int gcol = bn + wc + j * 16 + ml;
      const float bv_ = bias[gcol];
#pragma unroll
      for (int r = 0; r < 4; ++r) {
        const int grow = bm + wr + i * 16 + quad * 4 + r;
        const float v = acc[i][j][r] + bv_;
        const size_t idx = (size_t)grow * HID + gcol;
        if (z == 2) {
          vtmp[idx] = v;
        } else {
          const u16 hi = f2bf(v);
          const u16 lo = f2bf(v - bf2f(hi));
          if (z == 0) { qh[idx] = hi; ql[idx] = lo; }
          else        { kh[idx] = hi; kl[idx] = lo; }
        }
      }
    }
}

// ---- prep: transpose + split v: vT[b][n][c] = vtmp[b][c][n] ----
__global__ __launch_bounds__(256) void vtrans(const float* __restrict__ vtmp,
                                              u16* __restrict__ vTh, u16* __restrict__ vTl)
{
  __shared__ float t[32][33];
  const int b = blockIdx.z, n0 = blockIdx.x * 32, c0 = blockIdx.y * 32;
  const int tx = threadIdx.x & 31, ty = threadIdx.x >> 5;
  const float* src = vtmp + (size_t)b * SEQ * HID;
#pragma unroll
  for (int i = 0; i < 4; ++i)
    t[ty + 8 * i][tx] = src[(size_t)(c0 + ty + 8 * i) * HID + n0 + tx];
  __syncthreads();
#pragma unroll
  for (int i = 0; i < 4; ++i) {
    const float v = t[tx][ty + 8 * i];
    const size_t idx = (size_t)b * HID * SEQ + (size_t)(n0 + ty + 8 * i) * SEQ + c0 + tx;
    const u16 hi = f2bf(v);
    vTh[idx] = hi;
    vTl[idx] = f2bf(v - bf2f(hi));
  }
}

// ---- scores GEMM + fused rel-bias/scale/dist-mask epilogue (fp32 out) ----
__global__ __launch_bounds__(256, 2) void scores_mm(
    const u16* __restrict__ qh, const u16* __restrict__ ql,
    const u16* __restrict__ kh, const u16* __restrict__ kl, float* __restrict__ sc)
{
  __shared__ u16 lds[32768];
  const int z = blockIdx.z, b = z >> 2, hh = z & 3;
  const int bm = blockIdx.y * 128, bn = blockIdx.x * 128;
  const size_t abase = (size_t)(b * SEQ + bm) * HID + hh * 192;
  const size_t bbase = (size_t)(b * SEQ + bn) * HID + hh * 192;
  f4v acc[4][4];
#pragma unroll
  for (int i = 0; i < 4; ++i)
#pragma unroll
    for (int j = 0; j < 4; ++j) acc[i][j] = (f4v)0.f;
  mm_core128<6>(qh + abase, ql + abase, HID, kh + bbase, kl + bbase, HID, lds, acc);
  const int tid = threadIdx.x, w = tid >> 6, ln = tid & 63;
  const int ml = ln & 15, quad = ln >> 4;
  const int wr = (w >> 1) * 64, wc = (w & 1) * 64;
  float* sch = sc + (size_t)z * SEQ * SEQ;
#pragma unroll
  for (int i = 0; i < 4; ++i)
#pragma unroll
    for (int j = 0; j < 4; ++j) {
      const int scol = bn + wc + j * 16 + ml;
#pragma unroll
      for (int r = 0; r < 4; ++r) {
        const int srow = bm + wr + i * 16 + quad * 4 + r;
        const float dist = fabsf((float)(srow - scol));
        const float rel = __expf(-0.1f * fminf(dist, 5.0f));
        sch[(size_t)srow * SEQ + scol] =
            (acc[i][j][r] + rel) * INV_SQRT_D - 0.1f * dist;
      }
    }
}

// ---- softmax in-place, writes probs hi/lo bf16 into the same row bytes ----
__global__ __launch_bounds__(256) void softmax_split(float* __restrict__ sc)
{
  const int blk = blockIdx.x;
  const int z = blk >> 7, rg = blk & 127;
  const int tid = threadIdx.x;
  const int rr = tid >> 6, lane = tid & 63;
  const int r = rg * 4 + rr;
  float* row = sc + (size_t)z * SEQ * SEQ + (size_t)r * SEQ;
  float4 v0 = *(const float4*)(row + lane * 8);
  float4 v1 = *(const float4*)(row + lane * 8 + 4);
  float mx = fmaxf(fmaxf(fmaxf(v0.x, v0.y), fmaxf(v0.z, v0.w)),
                   fmaxf(fmaxf(v1.x, v1.y), fmaxf(v1.z, v1.w)));
#pragma unroll
  for (int o = 32; o > 0; o >>= 1) mx = fmaxf(mx, __shfl_xor(mx, o, 64));
  v0.x = __expf(v0.x - mx); v0.y = __expf(v0.y - mx);
  v0.z = __expf(v0.z - mx); v0.w = __expf(v0.w - mx);
  v1.x = __expf(v1.x - mx); v1.y = __expf(v1.y - mx);
  v1.z = __expf(v1.z - mx); v1.w = __expf(v1.w - mx);
  float s = v0.x + v0.y + v0.z + v0.w + v1.x + v1.y + v1.z + v1.w;
#pragma unroll
  for (int o = 32; o > 0; o >>= 1) s += __shfl_xor(s, o, 64);
  const float inv = 1.0f / s;
  float p[8] = {v0.x * inv, v0.y * inv, v0.z * inv, v0.w * inv,
                v1.x * inv, v1.y * inv, v1.z * inv, v1.w * inv};
  u16 hi[8], lo[8];
#pragma unroll
  for (int t = 0; t < 8; ++t) {
    hi[t] = f2bf(p[t]);
    lo[t] = f2bf(p[t] - bf2f(hi[t]));
  }
  u16* ph = (u16*)row;                       // [0,512) hi, [512,1024) lo
  ushort4* d0 = (ushort4*)&ph[lane * 8];
  d0[0] = make_ushort4(hi[0], hi[1], hi[2], hi[3]);
  d0[1] = make_ushort4(hi[4], hi[5], hi[6], hi[7]);
  ushort4* d1 = (ushort4*)&ph[512 + lane * 8];
  d1[0] = make_ushort4(lo[0], lo[1], lo[2], lo[3]);
  d1[1] = make_ushort4(lo[4], lo[5], lo[6], lo[7]);
}

// ---- PV GEMM: 64x192 tile, dbuf staging, one barrier/kstep ----
__global__ __launch_bounds__(256, 2) void pv_mm(
    const u16* __restrict__ pbase, const u16* __restrict__ vTh, const u16* __restrict__ vTl,
    u16* __restrict__ ch, u16* __restrict__ cl)
{
  __shared__ u16 lds[32768];   // per buf (16384): Ah@0 Al@2048 Bh@4096 Bl@10240
  const int z = blockIdx.y, b = z >> 2, hh = z & 3;
  const int bm = blockIdx.x * 64;
  const u16* ah_g = pbase + (size_t)z * SEQ * 1024 + (size_t)bm * 1024;
  const u16* al_g = ah_g + 512;
  const u16* bh_g = vTh + (size_t)b * HID * SEQ + (size_t)(hh * 192) * SEQ;
  const u16* bl_g = vTl + (size_t)b * HID * SEQ + (size_t)(hh * 192) * SEQ;
  const int tid = threadIdx.x, w = tid >> 6, ln = tid & 63;
  const int srow = ln >> 2;
  const int csw  = ((ln & 3) - (ln >> 3)) & 3;
  const int schunk = csw * 8;
  const int ml = ln & 15, quad = ln >> 4;
  const int fo2 = (((ln >> 4) + ((ln >> 1) & 3)) & 3) * 8;

  const u16* gp[8];
  int lpo[8];
#pragma unroll
  for (int s = 0; s < 8; ++s) {
    const int p = w * 8 + s;
    const u16* g; int l;
    if (p < 4)       { g = ah_g + (size_t)(p * 16 + srow) * 1024 + schunk; l = p * 512; }
    else if (p < 8)  { const int t = p - 4;  g = al_g + (size_t)(t * 16 + srow) * 1024 + schunk; l = 2048 + t * 512; }
    else if (p < 20) { const int t = p - 8;  g = bh_g + (size_t)(t * 16 + srow) * 512 + schunk; l = 4096 + t * 512; }
    else             { const int t = p - 20; g = bl_g + (size_t)(t * 16 + srow) * 512 + schunk; l = 10240 + t * 512; }
    gp[s] = g; lpo[s] = l + ln * 8;
  }
  s8v c[8];
#pragma unroll
  for (int s = 0; s < 8; ++s) c[s] = *(const s8v*)gp[s];
#pragma unroll
  for (int s = 0; s < 8; ++s) *(s8v*)&lds[lpo[s]] = c[s];
#pragma unroll
  for (int s = 0; s < 8; ++s) c[s] = *(const s8v*)(gp[s] + 32);
  __syncthreads();

  f4v acc[12];
#pragma unroll
  for (int j = 0; j < 12; ++j) acc[j] = (f4v)0.f;

  for (int ks = 0; ks < 16; ++ks) {
    u16* cur = lds + (ks & 1) * 16384;
    if (ks + 1 < 16) {
      u16* nxt = lds + ((ks + 1) & 1) * 16384;
#pragma unroll
      for (int s = 0; s < 8; ++s) *(s8v*)&nxt[lpo[s]] = c[s];
    }
    if (ks + 2 < 16) {
      const int k0 = (ks + 2) * 32;
#pragma unroll
      for (int s = 0; s < 8; ++s) c[s] = *(const s8v*)(gp[s] + k0);
    }
    const int ra = (w * 16 + ml) * 32 + fo2;
    const s8v a_h = *(const s8v*)&cur[ra];
    const s8v a_l = *(const s8v*)&cur[2048 + ra];
    s8v bh[12], bl[12];
#pragma unroll
    for (int j = 0; j < 12; ++j) {
      const int rb = (j * 16 + ml) * 32 + fo2;
      bh[j] = *(const s8v*)&cur[4096 + rb];
      bl[j] = *(const s8v*)&cur[10240 + rb];
    }
#pragma unroll
    for (int j = 0; j < 12; ++j)
      acc[j] = __builtin_amdgcn_mfma_f32_16x16x32_bf16(a_h, bh[j], acc[j], 0, 0, 0);
#pragma unroll
    for (int j = 0; j < 12; ++j)
      acc[j] = __builtin_amdgcn_mfma_f32_16x16x32_bf16(a_h, bl[j], acc[j], 0, 0, 0);
#pragma unroll
    for (int j = 0; j < 12; ++j)
      acc[j] = __builtin_amdgcn_mfma_f32_16x16x32_bf16(a_l, bh[j], acc[j], 0, 0, 0);
    __syncthreads();
  }
#pragma unroll
  for (int j = 0; j < 12; ++j) {
    const int gcol = hh * 192 + j * 16 + ml;
#pragma unroll
    for (int r = 0; r < 4; ++r) {
      const int m = bm + w * 16 + quad * 4 + r;
      const float v = acc[j][r];
      const size_t idx = (size_t)(b * SEQ + m) * HID + gcol;
      const u16 hi = f2bf(v);
      ch[idx] = hi;
      cl[idx] = f2bf(v - bf2f(hi));
    }
  }
}

// ---- projection GEMM + bias + residual -> h fp32 (XCD-swizzled, dbuf) ----
__global__ __launch_bounds__(256, 2) void proj_mm(
    const u16* __restrict__ ch, const u16* __restrict__ cl,
    const u16* __restrict__ WTh, const u16* __restrict__ WTl,
    const float* __restrict__ bo, const float* __restrict__ x, float* __restrict__ h)
{
  __shared__ u16 lds[32768];
  const int id = blockIdx.x;
  const int xcd = id & 7;
  const int s = id >> 3;            // 0..47
  const int bx = s % 6;
  const int yl = s / 6;             // 0..7
  const int bm = (yl * 8 + xcd) * 128;
  const int bn = bx * 128;
  const size_t wtoff = (size_t)3 * HID * HID + (size_t)bn * HID;
  f4v acc[4][4];
#pragma unroll
  for (int i = 0; i < 4; ++i)
#pragma unroll
    for (int j = 0; j < 4; ++j) acc[i][j] = (f4v)0.f;
  mm_core128<24>(ch + (size_t)bm * HID, cl + (size_t)bm * HID, HID,
                 WTh + wtoff, WTl + wtoff, HID, lds, acc);
  const int tid = threadIdx.x, w = tid >> 6, ln = tid & 63;
  const int ml = ln & 15, quad = ln >> 4;
  const int wr = (w >> 1) * 64, wc = (w & 1) * 64;
#pragma unroll
  for (int i = 0; i < 4; ++i)
#pragma unroll
    for (int j = 0; j < 4; ++j) {
      const int gcol = bn + wc + j * 16 + ml;
      const float bv_ = bo[gcol];
#pragma unroll
      for (int r = 0; r < 4; ++r) {
        const int grow = bm + wr + i * 16 + quad * 4 + r;
        const size_t idx = (size_t)grow * HID + gcol;
        h[idx] = acc[i][j][r] + bv_ + x[idx];
      }
    }
}

// ---- LayerNorm + 9-label classifier ----
__global__ __launch_bounds__(256) void ln_logits_kernel(
    const float* __restrict__ h, const float* __restrict__ g,
    const float* __restrict__ bta, const float* __restrict__ Ws,
    const float* __restrict__ bsv, float* __restrict__ span)
{
  const int row = blockIdx.x;
  const int tid = threadIdx.x;
  const float* hr = h + (size_t)row * HID;
  const float x0 = hr[tid], x1 = hr[tid + 256], x2 = hr[tid + 512];
  float s = x0 + x1 + x2;
  float sq = x0 * x0 + x1 * x1 + x2 * x2;
#pragma unroll
  for (int o = 32; o > 0; o >>= 1) { s += __shfl_down(s, o, 64); sq += __shfl_down(sq, o, 64); }
  __shared__ float red[8];
  __shared__ float smu, srs;
  const int wid = tid >> 6, lid = tid & 63;
  if (lid == 0) { red[wid] = s; red[4 + wid] = sq; }
  __syncthreads();
  if (tid == 0) {
    const float ts = red[0] + red[1] + red[2] + red[3];
    const float tq = red[4] + red[5] + red[6] + red[7];
    const float mu = ts / 768.0f;
    const float var = tq / 768.0f - mu * mu;
    smu = mu; srs = rsqrtf(var + 1e-5f);
  }
  __syncthreads();
  const float mu = smu, rs = srs;
  const float n0 = (x0 - mu) * rs * g[tid] + bta[tid];
  const float n1 = (x1 - mu) * rs * g[tid + 256] + bta[tid + 256];
  const float n2 = (x2 - mu) * rs * g[tid + 512] + bta[tid + 512];
  float pl[9];
#pragma unroll
  for (int l = 0; l < 9; ++l)
    pl[l] = n0 * Ws[(size_t)tid * 9 + l]
          + n1 * Ws[(size_t)(tid + 256) * 9 + l]
          + n2 * Ws[(size_t)(tid + 512) * 9 + l];
#pragma unroll
  for (int l = 0; l < 9; ++l)
#pragma unroll
    for (int o = 32; o > 0; o >>= 1) pl[l] += __shfl_down(pl[l], o, 64);
  __shared__ float lred[4][9];
  if (lid == 0) {
#pragma unroll
    for (int l = 0; l < 9; ++l) lred[wid][l] = pl[l];
  }
  __syncthreads();
  if (tid < 9) {
    span[(size_t)row * 9 + tid] =
        lred[0][tid] + lred[1][tid] + lred[2][tid] + lred[3][tid] + bsv[tid];
  }
}

// ---- entity-bias bump ----
__global__ __launch_bounds__(256) void bump_kernel(
    const float* __restrict__ span, const float* __restrict__ eb, float* __restrict__ out)
{
  const int idx = blockIdx.x * 256 + threadIdx.x;
  if (idx >= ROWS) return;
  const int j = idx & (SEQ - 1);
  const float* sl = span + (size_t)idx * 9;
  float v[9];
#pragma unroll
  for (int l = 0; l < 9; ++l) v[l] = sl[l];
  if (j >= 1) {
    const float* sp = sl - 9;
    float m = sp[0]; int am = 0;
#pragma unroll
    for (int l = 1; l < 9; ++l) { const float t = sp[l]; if (t > m) { m = t; am = l; } }
    if (am == 1) v[2] += 2.0f * eb[2];
  }
#pragma unroll
  for (int l = 0; l < 9; ++l) out[(size_t)idx * 9 + l] = v[l];
}

extern "C" void kernel_launch(void* const* d_in, const int* in_sizes, int n_in,
                              void* d_out, int out_size, void* d_ws, size_t ws_size,
                              hipStream_t stream)
{
  (void)in_sizes; (void)n_in; (void)out_size; (void)ws_size;
  const float* x   = (const float*)d_in[0];
  const float* Wq  = (const float*)d_in[1];
  const float* bq  = (const float*)d_in[2];
  const float* Wk  = (const float*)d_in[3];
  const float* bk  = (const float*)d_in[4];
  const float* Wv  = (const float*)d_in[5];
  const float* bv  = (const float*)d_in[6];
  const float* Wo  = (const float*)d_in[7];
  const float* bo  = (const float*)d_in[8];
  const float* lng = (const float*)d_in[9];
  const float* lnb = (const float*)d_in[10];
  const float* Ws  = (const float*)d_in[11];
  const float* bs  = (const float*)d_in[12];
  const float* eb  = (const float*)d_in[13];
  float* out = (float*)d_out;

  char* ws = (char*)d_ws;
  u16* xh  = (u16*)(ws + 0);
  u16* xl  = (u16*)(ws + 12582912);
  u16* vTh = xh;
  u16* vTl = xl;
  u16* WTh = (u16*)(ws + 25165824);
  u16* WTl = (u16*)(ws + 29884416);
  u16* qh  = (u16*)(ws + 34603008);
  u16* ql  = (u16*)(ws + 47185920);
  u16* kh  = (u16*)(ws + 59768832);
  u16* kl  = (u16*)(ws + 72351744);
  float* scb = (float*)(ws + 84934656);
  float* spanb = (float*)(ws + 152043520);
  float* vtmp = scb;
  float* hb = scb;
  u16* ctxh = qh;
  u16* ctxl = ql;

  splitx<<<dim3(1572864 / 256), 256, 0, stream>>>(x, xh, xl);
  wsplit<<<dim3(24, 24, 4), 256, 0, stream>>>(Wq, Wk, Wv, Wo, WTh, WTl);
  qkv_mm<<<dim3(1152), 256, 0, stream>>>(xh, xl, WTh, WTl, bq, bk, bv,
                                         qh, ql, kh, kl, vtmp);
  vtrans<<<dim3(24, 16, 16), 256, 0, stream>>>(vtmp, vTh, vTl);
  scores_mm<<<dim3(4, 4, 64), 256, 0, stream>>>(qh, ql, kh, kl, scb);
  softmax_split<<<dim3(8192), 256, 0, stream>>>(scb);
  pv_mm<<<dim3(8, 64), 256, 0, stream>>>((const u16*)scb, vTh, vTl, ctxh, ctxl);
  proj_mm<<<dim3(384), 256, 0, stream>>>(ctxh, ctxl, WTh, WTl, bo, x, hb);
  ln_logits_kernel<<<dim3(ROWS), 256, 0, stream>>>(hb, lng, lnb, Ws, bs, spanb);
  bump_kernel<<<dim3(ROWS / 256), 256, 0, stream>>>(spanb, eb, out);
}

// Round 9
// 275.530 us; speedup vs baseline: 2.1827x; 1.4160x over previous
//
#include <hip/hip_runtime.h>
#include <math.h>

#define SEQ 512
#define HID 768
#define NBATCH 16
#define ROWS 8192
#define INV_SQRT_D 0.07216878364870323f

typedef short s8v __attribute__((ext_vector_type(8)));
typedef _Float16 h8v __attribute__((ext_vector_type(8)));
typedef float f4v __attribute__((ext_vector_type(4)));
typedef unsigned short u16;

// ---- fp16 helper (RNE) ----
__device__ __forceinline__ u16 f2h(float f) {
  _Float16 h = (_Float16)f;
  return __builtin_bit_cast(u16, h);
}

// ---------------------------------------------------------------------------
// Single-precision fp16 GEMM core (R6-best structure): 128x128 tile, BK=32,
// VGPR prefetch, single 16KB LDS buffer, 2 barriers/kstep.
// Staging: wave (w>>1) picks A/B, (w&1) picks 64-row half; 4 s8v chunks/thread.
// LDS swizzle: (row,chunk) at row*32+((chunk+(row>>1))&3)*8 -> conflict-free
// b128 frag reads, contiguous ds_writes. 16 MFMA f16 per wave-kstep.
// ---------------------------------------------------------------------------
template <int KSTEPS>
__device__ __forceinline__ void mm_core128(
    const u16* __restrict__ A, const int lda,
    const u16* __restrict__ B, const int ldb,
    u16* lds, f4v (&acc)[4][4])
{
  const int tid = threadIdx.x;
  const int w = tid >> 6, ln = tid & 63;
  const u16* src = (w >> 1) ? B : A;
  const int ld = (w >> 1) ? ldb : lda;
  const int half = w & 1;
  const int srow = ln >> 2;
  const int csw  = ((ln & 3) - (ln >> 3)) & 3;
  const int ml = ln & 15, quad = ln >> 4;
  const int fo2 = ((quad + ((ln >> 1) & 3)) & 3) * 8;
  const int wr = (w >> 1) * 64, wc = (w & 1) * 64;

  const u16* gp[4];
  int lpo[4];
#pragma unroll
  for (int t = 0; t < 4; ++t) {
    const int row = half * 64 + t * 16 + srow;
    gp[t]  = src + (size_t)row * ld + csw * 8;
    lpo[t] = (w >> 1) * 4096 + half * 2048 + t * 512 + ln * 8;
  }
  s8v c[4];
#pragma unroll
  for (int t = 0; t < 4; ++t) c[t] = *(const s8v*)gp[t];

  for (int ks = 0; ks < KSTEPS; ++ks) {
    __syncthreads();                     // readers of prev step done
#pragma unroll
    for (int t = 0; t < 4; ++t) *(s8v*)&lds[lpo[t]] = c[t];
    __syncthreads();                     // staging visible
    if (ks + 1 < KSTEPS) {
      const int k0 = (ks + 1) * 32;
#pragma unroll
      for (int t = 0; t < 4; ++t) c[t] = *(const s8v*)(gp[t] + k0);
    }
    h8v a[4], b[4];
#pragma unroll
    for (int i = 0; i < 4; ++i)
      a[i] = *(const h8v*)&lds[(wr + i * 16 + ml) * 32 + fo2];
#pragma unroll
    for (int j = 0; j < 4; ++j)
      b[j] = *(const h8v*)&lds[4096 + (wc + j * 16 + ml) * 32 + fo2];
#pragma unroll
    for (int i = 0; i < 4; ++i)
#pragma unroll
      for (int j = 0; j < 4; ++j)
        acc[i][j] = __builtin_amdgcn_mfma_f32_16x16x32_f16(a[i], b[j], acc[i][j], 0, 0, 0);
  }
}

// ---- prep: x -> fp16 ----
__global__ __launch_bounds__(256) void splitx(const float* __restrict__ x,
                                              u16* __restrict__ xh)
{
  const int i = blockIdx.x * 256 + threadIdx.x;
  const float4 v = ((const float4*)x)[i];
  ((ushort4*)xh)[i] = make_ushort4(f2h(v.x), f2h(v.y), f2h(v.z), f2h(v.w));
}

// ---- prep: transpose weights: WT[z][n][k] = W_z[k][n], fp16 ----
__global__ __launch_bounds__(256) void wsplit(
    const float* __restrict__ Wq, const float* __restrict__ Wk,
    const float* __restrict__ Wv, const float* __restrict__ Wo,
    u16* __restrict__ WTh)
{
  __shared__ float t[32][33];
  const int z = blockIdx.z;
  const float* W = (z == 0) ? Wq : (z == 1) ? Wk : (z == 2) ? Wv : Wo;
  const int n0 = blockIdx.x * 32, k0 = blockIdx.y * 32;
  const int tx = threadIdx.x & 31, ty = threadIdx.x >> 5;
#pragma unroll
  for (int i = 0; i < 4; ++i)
    t[ty + 8 * i][tx] = W[(size_t)(k0 + ty + 8 * i) * HID + n0 + tx];
  __syncthreads();
#pragma unroll
  for (int i = 0; i < 4; ++i) {
    const float v = t[tx][ty + 8 * i];
    const size_t idx = (size_t)z * HID * HID + (size_t)(n0 + ty + 8 * i) * HID + k0 + tx;
    WTh[idx] = f2h(v);
  }
}

// ---- QKV GEMM, XCD-swizzled 1D grid (1152 blocks), fp16 core ----
__global__ __launch_bounds__(256, 3) void qkv_mm(
    const u16* __restrict__ xh, const u16* __restrict__ WTh,
    const float* __restrict__ bq, const float* __restrict__ bk, const float* __restrict__ bv,
    u16* __restrict__ qh, u16* __restrict__ kh, float* __restrict__ vtmp)
{
  __shared__ u16 lds[8192];
  const int id = blockIdx.x;
  const int xcd = id & 7;
  const int s = id >> 3;            // 0..143
  const int bx = s % 6;
  const int yl = (s / 6) & 7;
  const int z  = s / 48;
  const int bm = (yl * 8 + xcd) * 128;
  const int bn = bx * 128;
  const size_t wtoff = (size_t)z * HID * HID + (size_t)bn * HID;
  f4v acc[4][4];
#pragma unroll
  for (int i = 0; i < 4; ++i)
#pragma unroll
    for (int j = 0; j < 4; ++j) acc[i][j] = (f4v)0.f;
  mm_core128<24>(xh + (size_t)bm * HID, HID, WTh + wtoff, HID, lds, acc);
  const int tid = threadIdx.x, w = tid >> 6, ln = tid & 63;
  const int ml = ln & 15, quad = ln >> 4;
  const int wr = (w >> 1) * 64, wc = (w & 1) * 64;
  const float* bias = (z == 0) ? bq : (z == 1) ? bk : bv;
#pragma unroll
  for (int i = 0; i < 4; ++i)
#pragma unroll
    for (int j = 0; j < 4; ++j) {
      const int gcol = bn + wc + j * 16 + ml;
      const float bv_ = bias[gcol];
#pragma unroll
      for (int r = 0; r < 4; ++r) {
        const int grow = bm + wr + i * 16 + quad * 4 + r;
        const float v = acc[i][j][r] + bv_;
        const size_t idx = (size_t)grow * HID + gcol;
        if (z == 2)      vtmp[idx] = v;
        else if (z == 0) qh[idx] = f2h(v);
        else             kh[idx] = f2h(v);
      }
    }
}

// ---- prep: transpose v: vT[b][n][c] = vtmp[b][c][n], fp16 ----
__global__ __launch_bounds__(256) void vtrans(const float* __restrict__ vtmp,
                                              u16* __restrict__ vTh)
{
  __shared__ float t[32][33];
  const int b = blockIdx.z, n0 = blockIdx.x * 32, c0 = blockIdx.y * 32;
  const int tx = threadIdx.x & 31, ty = threadIdx.x >> 5;
  const float* src = vtmp + (size_t)b * SEQ * HID;
#pragma unroll
  for (int i = 0; i < 4; ++i)
    t[ty + 8 * i][tx] = src[(size_t)(c0 + ty + 8 * i) * HID + n0 + tx];
  __syncthreads();
#pragma unroll
  for (int i = 0; i < 4; ++i) {
    const float v = t[tx][ty + 8 * i];
    const size_t idx = (size_t)b * HID * SEQ + (size_t)(n0 + ty + 8 * i) * SEQ + c0 + tx;
    vTh[idx] = f2h(v);
  }
}

// ---- scores GEMM + fused rel-bias/scale/dist-mask epilogue (fp32 out) ----
__global__ __launch_bounds__(256, 3) void scores_mm(
    const u16* __restrict__ qh, const u16* __restrict__ kh, float* __restrict__ sc)
{
  __shared__ u16 lds[8192];
  const int z = blockIdx.z, b = z >> 2, hh = z & 3;
  const int bm = blockIdx.y * 128, bn = blockIdx.x * 128;
  const size_t abase = (size_t)(b * SEQ + bm) * HID + hh * 192;
  const size_t bbase = (size_t)(b * SEQ + bn) * HID + hh * 192;
  f4v acc[4][4];
#pragma unroll
  for (int i = 0; i < 4; ++i)
#pragma unroll
    for (int j = 0; j < 4; ++j) acc[i][j] = (f4v)0.f;
  mm_core128<6>(qh + abase, HID, kh + bbase, HID, lds, acc);
  const int tid = threadIdx.x, w = tid >> 6, ln = tid & 63;
  const int ml = ln & 15, quad = ln >> 4;
  const int wr = (w >> 1) * 64, wc = (w & 1) * 64;
  float* sch = sc + (size_t)z * SEQ * SEQ;
#pragma unroll
  for (int i = 0; i < 4; ++i)
#pragma unroll
    for (int j = 0; j < 4; ++j) {
      const int scol = bn + wc + j * 16 + ml;
#pragma unroll
      for (int r = 0; r < 4; ++r) {
        const int srow = bm + wr + i * 16 + quad * 4 + r;
        const float dist = fabsf((float)(srow - scol));
        const float rel = __expf(-0.1f * fminf(dist, 5.0f));
        sch[(size_t)srow * SEQ + scol] =
            (acc[i][j][r] + rel) * INV_SQRT_D - 0.1f * dist;
      }
    }
}

// ---- softmax in-place, writes fp16 probs into row bytes [0,512) ----
__global__ __launch_bounds__(256) void softmax_split(float* __restrict__ sc)
{
  const int blk = blockIdx.x;
  const int z = blk >> 7, rg = blk & 127;
  const int tid = threadIdx.x;
  const int rr = tid >> 6, lane = tid & 63;
  const int r = rg * 4 + rr;
  float* row = sc + (size_t)z * SEQ * SEQ + (size_t)r * SEQ;
  float4 v0 = *(const float4*)(row + lane * 8);
  float4 v1 = *(const float4*)(row + lane * 8 + 4);
  float mx = fmaxf(fmaxf(fmaxf(v0.x, v0.y), fmaxf(v0.z, v0.w)),
                   fmaxf(fmaxf(v1.x, v1.y), fmaxf(v1.z, v1.w)));
#pragma unroll
  for (int o = 32; o > 0; o >>= 1) mx = fmaxf(mx, __shfl_xor(mx, o, 64));
  v0.x = __expf(v0.x - mx); v0.y = __expf(v0.y - mx);
  v0.z = __expf(v0.z - mx); v0.w = __expf(v0.w - mx);
  v1.x = __expf(v1.x - mx); v1.y = __expf(v1.y - mx);
  v1.z = __expf(v1.z - mx); v1.w = __expf(v1.w - mx);
  float s = v0.x + v0.y + v0.z + v0.w + v1.x + v1.y + v1.z + v1.w;
#pragma unroll
  for (int o = 32; o > 0; o >>= 1) s += __shfl_xor(s, o, 64);
  const float inv = 1.0f / s;
  u16* ph = (u16*)row;                       // fp16 probs in [0,512)
  ushort4* d0 = (ushort4*)&ph[lane * 8];
  d0[0] = make_ushort4(f2h(v0.x * inv), f2h(v0.y * inv), f2h(v0.z * inv), f2h(v0.w * inv));
  d0[1] = make_ushort4(f2h(v1.x * inv), f2h(v1.y * inv), f2h(v1.z * inv), f2h(v1.w * inv));
}

// ---- PV GEMM: 64x192 tile, fp16, single 16KB buffer ----
__global__ __launch_bounds__(256, 3) void pv_mm(
    const u16* __restrict__ pbase, const u16* __restrict__ vTh, u16* __restrict__ ch)
{
  __shared__ u16 lds[8192];    // A 64x32 @0 (2048), B 192x32 @2048 (6144)
  const int z = blockIdx.y, b = z >> 2, hh = z & 3;
  const int bm = blockIdx.x * 64;
  const u16* ah_g = pbase + (size_t)z * SEQ * 1024 + (size_t)bm * 1024;  // ld 1024
  const u16* bh_g = vTh + (size_t)b * HID * SEQ + (size_t)(hh * 192) * SEQ; // ld 512
  const int tid = threadIdx.x, w = tid >> 6, ln = tid & 63;
  const int srow = ln >> 2;
  const int csw  = ((ln & 3) - (ln >> 3)) & 3;
  const int schunk = csw * 8;
  const int ml = ln & 15, quad = ln >> 4;
  const int fo2 = ((quad + ((ln >> 1) & 3)) & 3) * 8;

  const u16* gp[4];
  int lpo[4];
#pragma unroll
  for (int s = 0; s < 4; ++s) {
    const int p = w * 4 + s;
    if (p < 4) {
      gp[s]  = ah_g + (size_t)(p * 16 + srow) * 1024 + schunk;
      lpo[s] = p * 512 + ln * 8;
    } else {
      const int t = p - 4;
      gp[s]  = bh_g + (size_t)(t * 16 + srow) * 512 + schunk;
      lpo[s] = 2048 + t * 512 + ln * 8;
    }
  }
  s8v c[4];
#pragma unroll
  for (int s = 0; s < 4; ++s) c[s] = *(const s8v*)gp[s];

  f4v acc[12];
#pragma unroll
  for (int j = 0; j < 12; ++j) acc[j] = (f4v)0.f;

  for (int ks = 0; ks < 16; ++ks) {
    __syncthreads();
#pragma unroll
    for (int s = 0; s < 4; ++s) *(s8v*)&lds[lpo[s]] = c[s];
    __syncthreads();
    if (ks + 1 < 16) {
      const int k0 = (ks + 1) * 32;
#pragma unroll
      for (int s = 0; s < 4; ++s) c[s] = *(const s8v*)(gp[s] + k0);
    }
    const h8v a = *(const h8v*)&lds[(w * 16 + ml) * 32 + fo2];
    h8v bfrag[12];
#pragma unroll
    for (int j = 0; j < 12; ++j)
      bfrag[j] = *(const h8v*)&lds[2048 + (j * 16 + ml) * 32 + fo2];
#pragma unroll
    for (int j = 0; j < 12; ++j)
      acc[j] = __builtin_amdgcn_mfma_f32_16x16x32_f16(a, bfrag[j], acc[j], 0, 0, 0);
  }
#pragma unroll
  for (int j = 0; j < 12; ++j) {
    const int gcol = hh * 192 + j * 16 + ml;
#pragma unroll
    for (int r = 0; r < 4; ++r) {
      const int m = bm + w * 16 + quad * 4 + r;
      const size_t idx = (size_t)(b * SEQ + m) * HID + gcol;
      ch[idx] = f2h(acc[j][r]);
    }
  }
}

// ---- projection GEMM + bias + residual -> h fp32 (XCD-swizzled, fp16) ----
__global__ __launch_bounds__(256, 3) void proj_mm(
    const u16* __restrict__ ch, const u16* __restrict__ WTh,
    const float* __restrict__ bo, const float* __restrict__ x, float* __restrict__ h)
{
  __shared__ u16 lds[8192];
  const int id = blockIdx.x;
  const int xcd = id & 7;
  const int s = id >> 3;            // 0..47
  const int bx = s % 6;
  const int yl = s / 6;             // 0..7
  const int bm = (yl * 8 + xcd) * 128;
  const int bn = bx * 128;
  const size_t wtoff = (size_t)3 * HID * HID + (size_t)bn * HID;
  f4v acc[4][4];
#pragma unroll
  for (int i = 0; i < 4; ++i)
#pragma unroll
    for (int j = 0; j < 4; ++j) acc[i][j] = (f4v)0.f;
  mm_core128<24>(ch + (size_t)bm * HID, HID, WTh + wtoff, HID, lds, acc);
  const int tid = threadIdx.x, w = tid >> 6, ln = tid & 63;
  const int ml = ln & 15, quad = ln >> 4;
  const int wr = (w >> 1) * 64, wc = (w & 1) * 64;
#pragma unroll
  for (int i = 0; i < 4; ++i)
#pragma unroll
    for (int j = 0; j < 4; ++j) {
      const int gcol = bn + wc + j * 16 + ml;
      const float bv_ = bo[gcol];
#pragma unroll
      for (int r = 0; r < 4; ++r) {
        const int grow = bm + wr + i * 16 + quad * 4 + r;
        const size_t idx = (size_t)grow * HID + gcol;
        h[idx] = acc[i][j][r] + bv_ + x[idx];
      }
    }
}

// ---- LayerNorm + 9-label classifier ----
__global__ __launch_bounds__(256) void ln_logits_kernel(
    const float* __restrict__ h, const float* __restrict__ g,
    const float* __restrict__ bta, const float* __restrict__ Ws,
    const float* __restrict__ bsv, float* __restrict__ span)
{
  const int row = blockIdx.x;
  const int tid = threadIdx.x;
  const float* hr = h + (size_t)row * HID;
  const float x0 = hr[tid], x1 = hr[tid + 256], x2 = hr[tid + 512];
  float s = x0 + x1 + x2;
  float sq = x0 * x0 + x1 * x1 + x2 * x2;
#pragma unroll
  for (int o = 32; o > 0; o >>= 1) { s += __shfl_down(s, o, 64); sq += __shfl_down(sq, o, 64); }
  __shared__ float red[8];
  __shared__ float smu, srs;
  const int wid = tid >> 6, lid = tid & 63;
  if (lid == 0) { red[wid] = s; red[4 + wid] = sq; }
  __syncthreads();
  if (tid == 0) {
    const float ts = red[0] + red[1] + red[2] + red[3];
    const float tq = red[4] + red[5] + red[6] + red[7];
    const float mu = ts / 768.0f;
    const float var = tq / 768.0f - mu * mu;
    smu = mu; srs = rsqrtf(var + 1e-5f);
  }
  __syncthreads();
  const float mu = smu, rs = srs;
  const float n0 = (x0 - mu) * rs * g[tid] + bta[tid];
  const float n1 = (x1 - mu) * rs * g[tid + 256] + bta[tid + 256];
  const float n2 = (x2 - mu) * rs * g[tid + 512] + bta[tid + 512];
  float pl[9];
#pragma unroll
  for (int l = 0; l < 9; ++l)
    pl[l] = n0 * Ws[(size_t)tid * 9 + l]
          + n1 * Ws[(size_t)(tid + 256) * 9 + l]
          + n2 * Ws[(size_t)(tid + 512) * 9 + l];
#pragma unroll
  for (int l = 0; l < 9; ++l)
#pragma unroll
    for (int o = 32; o > 0; o >>= 1) pl[l] += __shfl_down(pl[l], o, 64);
  __shared__ float lred[4][9];
  if (lid == 0) {
#pragma unroll
    for (int l = 0; l < 9; ++l) lred[wid][l] = pl[l];
  }
  __syncthreads();
  if (tid < 9) {
    span[(size_t)row * 9 + tid] =
        lred[0][tid] + lred[1][tid] + lred[2][tid] + lred[3][tid] + bsv[tid];
  }
}

// ---- entity-bias bump ----
__global__ __launch_bounds__(256) void bump_kernel(
    const float* __restrict__ span, const float* __restrict__ eb, float* __restrict__ out)
{
  const int idx = blockIdx.x * 256 + threadIdx.x;
  if (idx >= ROWS) return;
  const int j = idx & (SEQ - 1);
  const float* sl = span + (size_t)idx * 9;
  float v[9];
#pragma unroll
  for (int l = 0; l < 9; ++l) v[l] = sl[l];
  if (j >= 1) {
    const float* sp = sl - 9;
    float m = sp[0]; int am = 0;
#pragma unroll
    for (int l = 1; l < 9; ++l) { const float t = sp[l]; if (t > m) { m = t; am = l; } }
    if (am == 1) v[2] += 2.0f * eb[2];
  }
#pragma unroll
  for (int l = 0; l < 9; ++l) out[(size_t)idx * 9 + l] = v[l];
}

extern "C" void kernel_launch(void* const* d_in, const int* in_sizes, int n_in,
                              void* d_out, int out_size, void* d_ws, size_t ws_size,
                              hipStream_t stream)
{
  (void)in_sizes; (void)n_in; (void)out_size; (void)ws_size;
  const float* x   = (const float*)d_in[0];
  const float* Wq  = (const float*)d_in[1];
  const float* bq  = (const float*)d_in[2];
  const float* Wk  = (const float*)d_in[3];
  const float* bk  = (const float*)d_in[4];
  const float* Wv  = (const float*)d_in[5];
  const float* bv  = (const float*)d_in[6];
  const float* Wo  = (const float*)d_in[7];
  const float* bo  = (const float*)d_in[8];
  const float* lng = (const float*)d_in[9];
  const float* lnb = (const float*)d_in[10];
  const float* Ws  = (const float*)d_in[11];
  const float* bs  = (const float*)d_in[12];
  const float* eb  = (const float*)d_in[13];
  float* out = (float*)d_out;

  char* ws = (char*)d_ws;
  u16* xh  = (u16*)(ws + 0);                       // fp16 x (12.6MB region)
  u16* vTh = xh;                                   // reuse after qkv
  u16* WTh = (u16*)(ws + 25165824);                // fp16 WT (4 matrices)
  u16* qh  = (u16*)(ws + 34603008);
  u16* kh  = (u16*)(ws + 59768832);
  float* scb = (float*)(ws + 84934656);            // scores / vtmp / h
  float* spanb = (float*)(ws + 152043520);
  float* vtmp = scb;
  float* hb = scb;
  u16* ctxh = qh;                                  // q dead after scores

  splitx<<<dim3(1572864 / 256), 256, 0, stream>>>(x, xh);
  wsplit<<<dim3(24, 24, 4), 256, 0, stream>>>(Wq, Wk, Wv, Wo, WTh);
  qkv_mm<<<dim3(1152), 256, 0, stream>>>(xh, WTh, bq, bk, bv, qh, kh, vtmp);
  vtrans<<<dim3(24, 16, 16), 256, 0, stream>>>(vtmp, vTh);
  scores_mm<<<dim3(4, 4, 64), 256, 0, stream>>>(qh, kh, scb);
  softmax_split<<<dim3(8192), 256, 0, stream>>>(scb);
  pv_mm<<<dim3(8, 64), 256, 0, stream>>>((const u16*)scb, vTh, ctxh);
  proj_mm<<<dim3(384), 256, 0, stream>>>(ctxh, WTh, bo, x, hb);
  ln_logits_kernel<<<dim3(ROWS), 256, 0, stream>>>(hb, lng, lnb, Ws, bs, spanb);
  bump_kernel<<<dim3(ROWS / 256), 256, 0, stream>>>(spanb, eb, out);
}

// Round 10
// 255.308 us; speedup vs baseline: 2.3556x; 1.0792x over previous
//
#include <hip/hip_runtime.h>
#include <math.h>

#define SEQ 512
#define HID 768
#define NBATCH 16
#define ROWS 8192
#define INV_SQRT_D 0.07216878364870323f

typedef short s8v __attribute__((ext_vector_type(8)));
typedef _Float16 h8v __attribute__((ext_vector_type(8)));
typedef float f4v __attribute__((ext_vector_type(4)));
typedef unsigned short u16;

// ---- fp16 helper (RNE) ----
__device__ __forceinline__ u16 f2h(float f) {
  _Float16 h = (_Float16)f;
  return __builtin_bit_cast(u16, h);
}

// ---------------------------------------------------------------------------
// fp16 GEMM core v4: BK=64 via PAIRED 32-wide sub-tiles, one barrier-pair per
// 64 logical K. LDS 32KB: sub0 {A@0,B@4096}, sub1 {A@8192,B@12288} (u16 idx).
// Per pair: write 8 prefetched s8v -> barrier -> prefetch next pair ->
// 32 MFMA/wave over both sub-tiles -> barrier. Layout identical to R9
// (swizzle (row,chunk)->row*32+((chunk+(row>>1))&3)*8, conflict-free).
// ---------------------------------------------------------------------------
template <int KSTEPS>   // number of 32-wide steps; must be even
__device__ __forceinline__ void mm_core128(
    const u16* __restrict__ A, const int lda,
    const u16* __restrict__ B, const int ldb,
    u16* lds, f4v (&acc)[4][4])
{
  const int tid = threadIdx.x;
  const int w = tid >> 6, ln = tid & 63;
  const u16* src = (w >> 1) ? B : A;
  const int ld = (w >> 1) ? ldb : lda;
  const int half = w & 1;
  const int srow = ln >> 2;
  const int csw  = ((ln & 3) - (ln >> 3)) & 3;
  const int ml = ln & 15, quad = ln >> 4;
  const int fo2 = ((quad + ((ln >> 1) & 3)) & 3) * 8;
  const int wr = (w >> 1) * 64, wc = (w & 1) * 64;

  const u16* gp[4];
  int lpo[4];
#pragma unroll
  for (int t = 0; t < 4; ++t) {
    const int row = half * 64 + t * 16 + srow;
    gp[t]  = src + (size_t)row * ld + csw * 8;
    lpo[t] = (w >> 1) * 4096 + half * 2048 + t * 512 + ln * 8;
  }
  s8v c[8];
#pragma unroll
  for (int t = 0; t < 4; ++t) {
    c[t]     = *(const s8v*)gp[t];
    c[4 + t] = *(const s8v*)(gp[t] + 32);
  }

  for (int kp = 0; kp < KSTEPS / 2; ++kp) {
    __syncthreads();                     // readers of prev pair done
#pragma unroll
    for (int t = 0; t < 4; ++t) {
      *(s8v*)&lds[lpo[t]]        = c[t];
      *(s8v*)&lds[8192 + lpo[t]] = c[4 + t];
    }
    __syncthreads();                     // staging visible
    if (kp + 1 < KSTEPS / 2) {
      const int k0 = (kp + 1) * 64;
#pragma unroll
      for (int t = 0; t < 4; ++t) {
        c[t]     = *(const s8v*)(gp[t] + k0);
        c[4 + t] = *(const s8v*)(gp[t] + k0 + 32);
      }
    }
#pragma unroll
    for (int sub = 0; sub < 2; ++sub) {
      const int so = sub * 8192;
      h8v a[4], b[4];
#pragma unroll
      for (int i = 0; i < 4; ++i)
        a[i] = *(const h8v*)&lds[so + (wr + i * 16 + ml) * 32 + fo2];
#pragma unroll
      for (int j = 0; j < 4; ++j)
        b[j] = *(const h8v*)&lds[so + 4096 + (wc + j * 16 + ml) * 32 + fo2];
#pragma unroll
      for (int i = 0; i < 4; ++i)
#pragma unroll
        for (int j = 0; j < 4; ++j)
          acc[i][j] = __builtin_amdgcn_mfma_f32_16x16x32_f16(a[i], b[j], acc[i][j], 0, 0, 0);
    }
  }
}

// ---- prep: x -> fp16 ----
__global__ __launch_bounds__(256) void splitx(const float* __restrict__ x,
                                              u16* __restrict__ xh)
{
  const int i = blockIdx.x * 256 + threadIdx.x;
  const float4 v = ((const float4*)x)[i];
  ((ushort4*)xh)[i] = make_ushort4(f2h(v.x), f2h(v.y), f2h(v.z), f2h(v.w));
}

// ---- prep: transpose weights: WT[z][n][k] = W_z[k][n], fp16 ----
__global__ __launch_bounds__(256) void wsplit(
    const float* __restrict__ Wq, const float* __restrict__ Wk,
    const float* __restrict__ Wv, const float* __restrict__ Wo,
    u16* __restrict__ WTh)
{
  __shared__ float t[32][33];
  const int z = blockIdx.z;
  const float* W = (z == 0) ? Wq : (z == 1) ? Wk : (z == 2) ? Wv : Wo;
  const int n0 = blockIdx.x * 32, k0 = blockIdx.y * 32;
  const int tx = threadIdx.x & 31, ty = threadIdx.x >> 5;
#pragma unroll
  for (int i = 0; i < 4; ++i)
    t[ty + 8 * i][tx] = W[(size_t)(k0 + ty + 8 * i) * HID + n0 + tx];
  __syncthreads();
#pragma unroll
  for (int i = 0; i < 4; ++i) {
    const float v = t[tx][ty + 8 * i];
    const size_t idx = (size_t)z * HID * HID + (size_t)(n0 + ty + 8 * i) * HID + k0 + tx;
    WTh[idx] = f2h(v);
  }
}

// ---- QKV GEMM, XCD-swizzled 1D grid (1152 blocks), fp16 BK=64 core ----
__global__ __launch_bounds__(256, 3) void qkv_mm(
    const u16* __restrict__ xh, const u16* __restrict__ WTh,
    const float* __restrict__ bq, const float* __restrict__ bk, const float* __restrict__ bv,
    u16* __restrict__ qh, u16* __restrict__ kh, float* __restrict__ vtmp)
{
  __shared__ u16 lds[16384];
  const int id = blockIdx.x;
  const int xcd = id & 7;
  const int s = id >> 3;            // 0..143
  const int bx = s % 6;
  const int yl = (s / 6) & 7;
  const int z  = s / 48;
  const int bm = (yl * 8 + xcd) * 128;
  const int bn = bx * 128;
  const size_t wtoff = (size_t)z * HID * HID + (size_t)bn * HID;
  f4v acc[4][4];
#pragma unroll
  for (int i = 0; i < 4; ++i)
#pragma unroll
    for (int j = 0; j < 4; ++j) acc[i][j] = (f4v)0.f;
  mm_core128<24>(xh + (size_t)bm * HID, HID, WTh + wtoff, HID, lds, acc);
  const int tid = threadIdx.x, w = tid >> 6, ln = tid & 63;
  const int ml = ln & 15, quad = ln >> 4;
  const int wr = (w >> 1) * 64, wc = (w & 1) * 64;
  const float* bias = (z == 0) ? bq : (z == 1) ? bk : bv;
#pragma unroll
  for (int i = 0; i < 4; ++i)
#pragma unroll
    for (int j = 0; j < 4; ++j) {
      const int gcol = bn + wc + j * 16 + ml;
      const float bv_ = bias[gcol];
#pragma unroll
      for (int r = 0; r < 4; ++r) {
        const int grow = bm + wr + i * 16 + quad * 4 + r;
        const float v = acc[i][j][r] + bv_;
        const size_t idx = (size_t)grow * HID + gcol;
        if (z == 2)      vtmp[idx] = v;
        else if (z == 0) qh[idx] = f2h(v);
        else             kh[idx] = f2h(v);
      }
    }
}

// ---- prep: transpose v: vT[b][n][c] = vtmp[b][c][n], fp16 ----
__global__ __launch_bounds__(256) void vtrans(const float* __restrict__ vtmp,
                                              u16* __restrict__ vTh)
{
  __shared__ float t[32][33];
  const int b = blockIdx.z, n0 = blockIdx.x * 32, c0 = blockIdx.y * 32;
  const int tx = threadIdx.x & 31, ty = threadIdx.x >> 5;
  const float* src = vtmp + (size_t)b * SEQ * HID;
#pragma unroll
  for (int i = 0; i < 4; ++i)
    t[ty + 8 * i][tx] = src[(size_t)(c0 + ty + 8 * i) * HID + n0 + tx];
  __syncthreads();
#pragma unroll
  for (int i = 0; i < 4; ++i) {
    const float v = t[tx][ty + 8 * i];
    const size_t idx = (size_t)b * HID * SEQ + (size_t)(n0 + ty + 8 * i) * SEQ + c0 + tx;
    vTh[idx] = f2h(v);
  }
}

// ---- scores GEMM + fused rel-bias/scale/dist-mask epilogue (fp32 out) ----
__global__ __launch_bounds__(256, 3) void scores_mm(
    const u16* __restrict__ qh, const u16* __restrict__ kh, float* __restrict__ sc)
{
  __shared__ u16 lds[16384];
  const int z = blockIdx.z, b = z >> 2, hh = z & 3;
  const int bm = blockIdx.y * 128, bn = blockIdx.x * 128;
  const size_t abase = (size_t)(b * SEQ + bm) * HID + hh * 192;
  const size_t bbase = (size_t)(b * SEQ + bn) * HID + hh * 192;
  f4v acc[4][4];
#pragma unroll
  for (int i = 0; i < 4; ++i)
#pragma unroll
    for (int j = 0; j < 4; ++j) acc[i][j] = (f4v)0.f;
  mm_core128<6>(qh + abase, HID, kh + bbase, HID, lds, acc);
  const int tid = threadIdx.x, w = tid >> 6, ln = tid & 63;
  const int ml = ln & 15, quad = ln >> 4;
  const int wr = (w >> 1) * 64, wc = (w & 1) * 64;
  float* sch = sc + (size_t)z * SEQ * SEQ;
#pragma unroll
  for (int i = 0; i < 4; ++i)
#pragma unroll
    for (int j = 0; j < 4; ++j) {
      const int scol = bn + wc + j * 16 + ml;
#pragma unroll
      for (int r = 0; r < 4; ++r) {
        const int srow = bm + wr + i * 16 + quad * 4 + r;
        const float dist = fabsf((float)(srow - scol));
        const float rel = __expf(-0.1f * fminf(dist, 5.0f));
        sch[(size_t)srow * SEQ + scol] =
            (acc[i][j][r] + rel) * INV_SQRT_D - 0.1f * dist;
      }
    }
}

// ---- softmax in-place, writes fp16 probs into row bytes [0,512) ----
__global__ __launch_bounds__(256) void softmax_split(float* __restrict__ sc)
{
  const int blk = blockIdx.x;
  const int z = blk >> 7, rg = blk & 127;
  const int tid = threadIdx.x;
  const int rr = tid >> 6, lane = tid & 63;
  const int r = rg * 4 + rr;
  float* row = sc + (size_t)z * SEQ * SEQ + (size_t)r * SEQ;
  float4 v0 = *(const float4*)(row + lane * 8);
  float4 v1 = *(const float4*)(row + lane * 8 + 4);
  float mx = fmaxf(fmaxf(fmaxf(v0.x, v0.y), fmaxf(v0.z, v0.w)),
                   fmaxf(fmaxf(v1.x, v1.y), fmaxf(v1.z, v1.w)));
#pragma unroll
  for (int o = 32; o > 0; o >>= 1) mx = fmaxf(mx, __shfl_xor(mx, o, 64));
  v0.x = __expf(v0.x - mx); v0.y = __expf(v0.y - mx);
  v0.z = __expf(v0.z - mx); v0.w = __expf(v0.w - mx);
  v1.x = __expf(v1.x - mx); v1.y = __expf(v1.y - mx);
  v1.z = __expf(v1.z - mx); v1.w = __expf(v1.w - mx);
  float s = v0.x + v0.y + v0.z + v0.w + v1.x + v1.y + v1.z + v1.w;
#pragma unroll
  for (int o = 32; o > 0; o >>= 1) s += __shfl_xor(s, o, 64);
  const float inv = 1.0f / s;
  u16* ph = (u16*)row;                       // fp16 probs in [0,512)
  ushort4* d0 = (ushort4*)&ph[lane * 8];
  d0[0] = make_ushort4(f2h(v0.x * inv), f2h(v0.y * inv), f2h(v0.z * inv), f2h(v0.w * inv));
  d0[1] = make_ushort4(f2h(v1.x * inv), f2h(v1.y * inv), f2h(v1.z * inv), f2h(v1.w * inv));
}

// ---- PV GEMM: 64x192 tile, fp16, paired sub-tiles (BK=64) ----
__global__ __launch_bounds__(256, 3) void pv_mm(
    const u16* __restrict__ pbase, const u16* __restrict__ vTh, u16* __restrict__ ch)
{
  __shared__ u16 lds[16384];   // sub0: A@0(2048) B@2048(6144); sub1: +8192
  const int z = blockIdx.y, b = z >> 2, hh = z & 3;
  const int bm = blockIdx.x * 64;
  const u16* ah_g = pbase + (size_t)z * SEQ * 1024 + (size_t)bm * 1024;  // ld 1024
  const u16* bh_g = vTh + (size_t)b * HID * SEQ + (size_t)(hh * 192) * SEQ; // ld 512
  const int tid = threadIdx.x, w = tid >> 6, ln = tid & 63;
  const int srow = ln >> 2;
  const int csw  = ((ln & 3) - (ln >> 3)) & 3;
  const int schunk = csw * 8;
  const int ml = ln & 15, quad = ln >> 4;
  const int fo2 = ((quad + ((ln >> 1) & 3)) & 3) * 8;

  const u16* gp[4];
  int lpo[4];
#pragma unroll
  for (int s = 0; s < 4; ++s) {
    const int p = w * 4 + s;
    if (p < 4) {
      gp[s]  = ah_g + (size_t)(p * 16 + srow) * 1024 + schunk;
      lpo[s] = p * 512 + ln * 8;
    } else {
      const int t = p - 4;
      gp[s]  = bh_g + (size_t)(t * 16 + srow) * 512 + schunk;
      lpo[s] = 2048 + t * 512 + ln * 8;
    }
  }
  s8v c[8];
#pragma unroll
  for (int s = 0; s < 4; ++s) {
    c[s]     = *(const s8v*)gp[s];
    c[4 + s] = *(const s8v*)(gp[s] + 32);
  }

  f4v acc[12];
#pragma unroll
  for (int j = 0; j < 12; ++j) acc[j] = (f4v)0.f;

  for (int kp = 0; kp < 8; ++kp) {
    __syncthreads();
#pragma unroll
    for (int s = 0; s < 4; ++s) {
      *(s8v*)&lds[lpo[s]]        = c[s];
      *(s8v*)&lds[8192 + lpo[s]] = c[4 + s];
    }
    __syncthreads();
    if (kp + 1 < 8) {
      const int k0 = (kp + 1) * 64;
#pragma unroll
      for (int s = 0; s < 4; ++s) {
        c[s]     = *(const s8v*)(gp[s] + k0);
        c[4 + s] = *(const s8v*)(gp[s] + k0 + 32);
      }
    }
#pragma unroll
    for (int sub = 0; sub < 2; ++sub) {
      const int so = sub * 8192;
      const h8v a = *(const h8v*)&lds[so + (w * 16 + ml) * 32 + fo2];
      h8v bfrag[12];
#pragma unroll
      for (int j = 0; j < 12; ++j)
        bfrag[j] = *(const h8v*)&lds[so + 2048 + (j * 16 + ml) * 32 + fo2];
#pragma unroll
      for (int j = 0; j < 12; ++j)
        acc[j] = __builtin_amdgcn_mfma_f32_16x16x32_f16(a, bfrag[j], acc[j], 0, 0, 0);
    }
  }
#pragma unroll
  for (int j = 0; j < 12; ++j) {
    const int gcol = hh * 192 + j * 16 + ml;
#pragma unroll
    for (int r = 0; r < 4; ++r) {
      const int m = bm + w * 16 + quad * 4 + r;
      const size_t idx = (size_t)(b * SEQ + m) * HID + gcol;
      ch[idx] = f2h(acc[j][r]);
    }
  }
}

// ---- projection GEMM + bias + residual -> h fp32 (XCD-swizzled, fp16) ----
__global__ __launch_bounds__(256, 3) void proj_mm(
    const u16* __restrict__ ch, const u16* __restrict__ WTh,
    const float* __restrict__ bo, const float* __restrict__ x, float* __restrict__ h)
{
  __shared__ u16 lds[16384];
  const int id = blockIdx.x;
  const int xcd = id & 7;
  const int s = id >> 3;            // 0..47
  const int bx = s % 6;
  const int yl = s / 6;             // 0..7
  const int bm = (yl * 8 + xcd) * 128;
  const int bn = bx * 128;
  const size_t wtoff = (size_t)3 * HID * HID + (size_t)bn * HID;
  f4v acc[4][4];
#pragma unroll
  for (int i = 0; i < 4; ++i)
#pragma unroll
    for (int j = 0; j < 4; ++j) acc[i][j] = (f4v)0.f;
  mm_core128<24>(ch + (size_t)bm * HID, HID, WTh + wtoff, HID, lds, acc);
  const int tid = threadIdx.x, w = tid >> 6, ln = tid & 63;
  const int ml = ln & 15, quad = ln >> 4;
  const int wr = (w >> 1) * 64, wc = (w & 1) * 64;
#pragma unroll
  for (int i = 0; i < 4; ++i)
#pragma unroll
    for (int j = 0; j < 4; ++j) {
      const int gcol = bn + wc + j * 16 + ml;
      const float bv_ = bo[gcol];
#pragma unroll
      for (int r = 0; r < 4; ++r) {
        const int grow = bm + wr + i * 16 + quad * 4 + r;
        const size_t idx = (size_t)grow * HID + gcol;
        h[idx] = acc[i][j][r] + bv_ + x[idx];
      }
    }
}

// ---- LayerNorm + 9-label classifier ----
__global__ __launch_bounds__(256) void ln_logits_kernel(
    const float* __restrict__ h, const float* __restrict__ g,
    const float* __restrict__ bta, const float* __restrict__ Ws,
    const float* __restrict__ bsv, float* __restrict__ span)
{
  const int row = blockIdx.x;
  const int tid = threadIdx.x;
  const float* hr = h + (size_t)row * HID;
  const float x0 = hr[tid], x1 = hr[tid + 256], x2 = hr[tid + 512];
  float s = x0 + x1 + x2;
  float sq = x0 * x0 + x1 * x1 + x2 * x2;
#pragma unroll
  for (int o = 32; o > 0; o >>= 1) { s += __shfl_down(s, o, 64); sq += __shfl_down(sq, o, 64); }
  __shared__ float red[8];
  __shared__ float smu, srs;
  const int wid = tid >> 6, lid = tid & 63;
  if (lid == 0) { red[wid] = s; red[4 + wid] = sq; }
  __syncthreads();
  if (tid == 0) {
    const float ts = red[0] + red[1] + red[2] + red[3];
    const float tq = red[4] + red[5] + red[6] + red[7];
    const float mu = ts / 768.0f;
    const float var = tq / 768.0f - mu * mu;
    smu = mu; srs = rsqrtf(var + 1e-5f);
  }
  __syncthreads();
  const float mu = smu, rs = srs;
  const float n0 = (x0 - mu) * rs * g[tid] + bta[tid];
  const float n1 = (x1 - mu) * rs * g[tid + 256] + bta[tid + 256];
  const float n2 = (x2 - mu) * rs * g[tid + 512] + bta[tid + 512];
  float pl[9];
#pragma unroll
  for (int l = 0; l < 9; ++l)
    pl[l] = n0 * Ws[(size_t)tid * 9 + l]
          + n1 * Ws[(size_t)(tid + 256) * 9 + l]
          + n2 * Ws[(size_t)(tid + 512) * 9 + l];
#pragma unroll
  for (int l = 0; l < 9; ++l)
#pragma unroll
    for (int o = 32; o > 0; o >>= 1) pl[l] += __shfl_down(pl[l], o, 64);
  __shared__ float lred[4][9];
  if (lid == 0) {
#pragma unroll
    for (int l = 0; l < 9; ++l) lred[wid][l] = pl[l];
  }
  __syncthreads();
  if (tid < 9) {
    span[(size_t)row * 9 + tid] =
        lred[0][tid] + lred[1][tid] + lred[2][tid] + lred[3][tid] + bsv[tid];
  }
}

// ---- entity-bias bump ----
__global__ __launch_bounds__(256) void bump_kernel(
    const float* __restrict__ span, const float* __restrict__ eb, float* __restrict__ out)
{
  const int idx = blockIdx.x * 256 + threadIdx.x;
  if (idx >= ROWS) return;
  const int j = idx & (SEQ - 1);
  const float* sl = span + (size_t)idx * 9;
  float v[9];
#pragma unroll
  for (int l = 0; l < 9; ++l) v[l] = sl[l];
  if (j >= 1) {
    const float* sp = sl - 9;
    float m = sp[0]; int am = 0;
#pragma unroll
    for (int l = 1; l < 9; ++l) { const float t = sp[l]; if (t > m) { m = t; am = l; } }
    if (am == 1) v[2] += 2.0f * eb[2];
  }
#pragma unroll
  for (int l = 0; l < 9; ++l) out[(size_t)idx * 9 + l] = v[l];
}

extern "C" void kernel_launch(void* const* d_in, const int* in_sizes, int n_in,
                              void* d_out, int out_size, void* d_ws, size_t ws_size,
                              hipStream_t stream)
{
  (void)in_sizes; (void)n_in; (void)out_size; (void)ws_size;
  const float* x   = (const float*)d_in[0];
  const float* Wq  = (const float*)d_in[1];
  const float* bq  = (const float*)d_in[2];
  const float* Wk  = (const float*)d_in[3];
  const float* bk  = (const float*)d_in[4];
  const float* Wv  = (const float*)d_in[5];
  const float* bv  = (const float*)d_in[6];
  const float* Wo  = (const float*)d_in[7];
  const float* bo  = (const float*)d_in[8];
  const float* lng = (const float*)d_in[9];
  const float* lnb = (const float*)d_in[10];
  const float* Ws  = (const float*)d_in[11];
  const float* bs  = (const float*)d_in[12];
  const float* eb  = (const float*)d_in[13];
  float* out = (float*)d_out;

  char* ws = (char*)d_ws;
  u16* xh  = (u16*)(ws + 0);                       // fp16 x
  u16* vTh = xh;                                   // reuse after qkv
  u16* WTh = (u16*)(ws + 25165824);                // fp16 WT (4 matrices)
  u16* qh  = (u16*)(ws + 34603008);
  u16* kh  = (u16*)(ws + 59768832);
  float* scb = (float*)(ws + 84934656);            // scores / vtmp / h
  float* spanb = (float*)(ws + 152043520);
  float* vtmp = scb;
  float* hb = scb;
  u16* ctxh = qh;                                  // q dead after scores

  splitx<<<dim3(1572864 / 256), 256, 0, stream>>>(x, xh);
  wsplit<<<dim3(24, 24, 4), 256, 0, stream>>>(Wq, Wk, Wv, Wo, WTh);
  qkv_mm<<<dim3(1152), 256, 0, stream>>>(xh, WTh, bq, bk, bv, qh, kh, vtmp);
  vtrans<<<dim3(24, 16, 16), 256, 0, stream>>>(vtmp, vTh);
  scores_mm<<<dim3(4, 4, 64), 256, 0, stream>>>(qh, kh, scb);
  softmax_split<<<dim3(8192), 256, 0, stream>>>(scb);
  pv_mm<<<dim3(8, 64), 256, 0, stream>>>((const u16*)scb, vTh, ctxh);
  proj_mm<<<dim3(384), 256, 0, stream>>>(ctxh, WTh, bo, x, hb);
  ln_logits_kernel<<<dim3(ROWS), 256, 0, stream>>>(hb, lng, lnb, Ws, bs, spanb);
  bump_kernel<<<dim3(ROWS / 256), 256, 0, stream>>>(spanb, eb, out);
}

// Round 11
// 244.638 us; speedup vs baseline: 2.4583x; 1.0436x over previous
//
#include <hip/hip_runtime.h>
#include <math.h>

#define SEQ 512
#define HID 768
#define NBATCH 16
#define ROWS 8192
#define INV_SQRT_D 0.07216878364870323f

typedef short s8v __attribute__((ext_vector_type(8)));
typedef _Float16 h8v __attribute__((ext_vector_type(8)));
typedef float f4v __attribute__((ext_vector_type(4)));
typedef unsigned short u16;

// ---- fp16 helper (RNE) ----
__device__ __forceinline__ u16 f2h(float f) {
  _Float16 h = (_Float16)f;
  return __builtin_bit_cast(u16, h);
}

// ---------------------------------------------------------------------------
// fp16 GEMM core (R10): BK=64 via paired 32-wide sub-tiles, one barrier-pair
// per 64 K. LDS 32KB: sub0 {A@0,B@4096}, sub1 {A@8192,B@12288} (u16 idx).
// Swizzle (row,chunk)->row*32+((chunk+(row>>1))&3)*8: conflict-free b128 reads.
// ---------------------------------------------------------------------------
template <int KSTEPS>   // number of 32-wide steps; must be even
__device__ __forceinline__ void mm_core128(
    const u16* __restrict__ A, const int lda,
    const u16* __restrict__ B, const int ldb,
    u16* lds, f4v (&acc)[4][4])
{
  const int tid = threadIdx.x;
  const int w = tid >> 6, ln = tid & 63;
  const u16* src = (w >> 1) ? B : A;
  const int ld = (w >> 1) ? ldb : lda;
  const int half = w & 1;
  const int srow = ln >> 2;
  const int csw  = ((ln & 3) - (ln >> 3)) & 3;
  const int ml = ln & 15, quad = ln >> 4;
  const int fo2 = ((quad + ((ln >> 1) & 3)) & 3) * 8;
  const int wr = (w >> 1) * 64, wc = (w & 1) * 64;

  const u16* gp[4];
  int lpo[4];
#pragma unroll
  for (int t = 0; t < 4; ++t) {
    const int row = half * 64 + t * 16 + srow;
    gp[t]  = src + (size_t)row * ld + csw * 8;
    lpo[t] = (w >> 1) * 4096 + half * 2048 + t * 512 + ln * 8;
  }
  s8v c[8];
#pragma unroll
  for (int t = 0; t < 4; ++t) {
    c[t]     = *(const s8v*)gp[t];
    c[4 + t] = *(const s8v*)(gp[t] + 32);
  }

  for (int kp = 0; kp < KSTEPS / 2; ++kp) {
    __syncthreads();
#pragma unroll
    for (int t = 0; t < 4; ++t) {
      *(s8v*)&lds[lpo[t]]        = c[t];
      *(s8v*)&lds[8192 + lpo[t]] = c[4 + t];
    }
    __syncthreads();
    if (kp + 1 < KSTEPS / 2) {
      const int k0 = (kp + 1) * 64;
#pragma unroll
      for (int t = 0; t < 4; ++t) {
        c[t]     = *(const s8v*)(gp[t] + k0);
        c[4 + t] = *(const s8v*)(gp[t] + k0 + 32);
      }
    }
#pragma unroll
    for (int sub = 0; sub < 2; ++sub) {
      const int so = sub * 8192;
      h8v a[4], b[4];
#pragma unroll
      for (int i = 0; i < 4; ++i)
        a[i] = *(const h8v*)&lds[so + (wr + i * 16 + ml) * 32 + fo2];
#pragma unroll
      for (int j = 0; j < 4; ++j)
        b[j] = *(const h8v*)&lds[so + 4096 + (wc + j * 16 + ml) * 32 + fo2];
#pragma unroll
      for (int i = 0; i < 4; ++i)
#pragma unroll
        for (int j = 0; j < 4; ++j)
          acc[i][j] = __builtin_amdgcn_mfma_f32_16x16x32_f16(a[i], b[j], acc[i][j], 0, 0, 0);
    }
  }
}

// ---- prep: x -> fp16 ----
__global__ __launch_bounds__(256) void splitx(const float* __restrict__ x,
                                              u16* __restrict__ xh)
{
  const int i = blockIdx.x * 256 + threadIdx.x;
  const float4 v = ((const float4*)x)[i];
  ((ushort4*)xh)[i] = make_ushort4(f2h(v.x), f2h(v.y), f2h(v.z), f2h(v.w));
}

// ---- prep: transpose weights: WT[z][n][k] = W_z[k][n], fp16 ----
__global__ __launch_bounds__(256) void wsplit(
    const float* __restrict__ Wq, const float* __restrict__ Wk,
    const float* __restrict__ Wv, const float* __restrict__ Wo,
    u16* __restrict__ WTh)
{
  __shared__ float t[32][33];
  const int z = blockIdx.z;
  const float* W = (z == 0) ? Wq : (z == 1) ? Wk : (z == 2) ? Wv : Wo;
  const int n0 = blockIdx.x * 32, k0 = blockIdx.y * 32;
  const int tx = threadIdx.x & 31, ty = threadIdx.x >> 5;
#pragma unroll
  for (int i = 0; i < 4; ++i)
    t[ty + 8 * i][tx] = W[(size_t)(k0 + ty + 8 * i) * HID + n0 + tx];
  __syncthreads();
#pragma unroll
  for (int i = 0; i < 4; ++i) {
    const float v = t[tx][ty + 8 * i];
    const size_t idx = (size_t)z * HID * HID + (size_t)(n0 + ty + 8 * i) * HID + k0 + tx;
    WTh[idx] = f2h(v);
  }
}

// ---- QKV GEMM, XCD-swizzled 1D grid (1152 blocks), fp16 BK=64 core ----
__global__ __launch_bounds__(256, 3) void qkv_mm(
    const u16* __restrict__ xh, const u16* __restrict__ WTh,
    const float* __restrict__ bq, const float* __restrict__ bk, const float* __restrict__ bv,
    u16* __restrict__ qh, u16* __restrict__ kh, u16* __restrict__ vtmp16)
{
  __shared__ u16 lds[16384];
  const int id = blockIdx.x;
  const int xcd = id & 7;
  const int s = id >> 3;            // 0..143
  const int bx = s % 6;
  const int yl = (s / 6) & 7;
  const int z  = s / 48;
  const int bm = (yl * 8 + xcd) * 128;
  const int bn = bx * 128;
  const size_t wtoff = (size_t)z * HID * HID + (size_t)bn * HID;
  f4v acc[4][4];
#pragma unroll
  for (int i = 0; i < 4; ++i)
#pragma unroll
    for (int j = 0; j < 4; ++j) acc[i][j] = (f4v)0.f;
  mm_core128<24>(xh + (size_t)bm * HID, HID, WTh + wtoff, HID, lds, acc);
  const int tid = threadIdx.x, w = tid >> 6, ln = tid & 63;
  const int ml = ln & 15, quad = ln >> 4;
  const int wr = (w >> 1) * 64, wc = (w & 1) * 64;
  const float* bias = (z == 0) ? bq : (z == 1) ? bk : bv;
#pragma unroll
  for (int i = 0; i < 4; ++i)
#pragma unroll
    for (int j = 0; j < 4; ++j) {
      const int gcol = bn + wc + j * 16 + ml;
      const float bv_ = bias[gcol];
#pragma unroll
      for (int r = 0; r < 4; ++r) {
        const int grow = bm + wr + i * 16 + quad * 4 + r;
        const float v = acc[i][j][r] + bv_;
        const size_t idx = (size_t)grow * HID + gcol;
        if (z == 2)      vtmp16[idx] = f2h(v);
        else if (z == 0) qh[idx] = f2h(v);
        else             kh[idx] = f2h(v);
      }
    }
}

// ---- prep: transpose v (fp16 passthrough): vT[b][n][c] = vtmp16[b][c][n] ----
__global__ __launch_bounds__(256) void vtrans(const u16* __restrict__ vtmp16,
                                              u16* __restrict__ vTh)
{
  __shared__ u16 t[32][33];
  const int b = blockIdx.z, n0 = blockIdx.x * 32, c0 = blockIdx.y * 32;
  const int tx = threadIdx.x & 31, ty = threadIdx.x >> 5;
  const u16* src = vtmp16 + (size_t)b * SEQ * HID;
#pragma unroll
  for (int i = 0; i < 4; ++i)
    t[ty + 8 * i][tx] = src[(size_t)(c0 + ty + 8 * i) * HID + n0 + tx];
  __syncthreads();
#pragma unroll
  for (int i = 0; i < 4; ++i) {
    const size_t idx = (size_t)b * HID * SEQ + (size_t)(n0 + ty + 8 * i) * SEQ + c0 + tx;
    vTh[idx] = t[tx][ty + 8 * i];
  }
}

// ---------------------------------------------------------------------------
// FUSED scores+softmax: block = 32 Q-rows x ALL 512 K-cols (full softmax rows
// in-register). K=192 in 6 BK=32 steps (VGPR prefetch, 2 barriers/kstep).
// LDS: A 32x32 @0 (1024 u16), B 512x32 @1024 (16384 u16), swizzled as core.
// Epilogue: rel-bias/scale/dist-mask, row max (quad shfl-xor + 4-wave LDS
// reduce), exp, sum, normalize -> write fp16 P (ld 512). acc: 16 f4v/thread.
// ---------------------------------------------------------------------------
__global__ __launch_bounds__(256, 2) void scores_softmax(
    const u16* __restrict__ qh, const u16* __restrict__ kh, u16* __restrict__ P)
{
  __shared__ u16 lds[17408];
  __shared__ float red[4][32];
  const int z = blockIdx.y, b = z >> 2, hh = z & 3;
  const int bm = blockIdx.x * 32;
  const int tid = threadIdx.x, w = tid >> 6, ln = tid & 63;
  const int ml = ln & 15, quad = ln >> 4;
  const int fo2 = ((quad + ((ml >> 1) & 3)) & 3) * 8;
  const u16* qbase = qh + (size_t)(b * SEQ + bm) * HID + hh * 192;
  const u16* kbase = kh + (size_t)(b * SEQ) * HID + hh * 192;

  // staging: B: 8 chunks/thread, row t*64+(tid>>2), stored chunk tid&3
  const int brow0 = tid >> 2, bsc = tid & 3;
  const u16* bgp[8];
  int blo[8];
#pragma unroll
  for (int t = 0; t < 8; ++t) {
    const int row = t * 64 + brow0;
    const int lc = (bsc - (row >> 1)) & 3;
    bgp[t] = kbase + (size_t)row * HID + lc * 8;
    blo[t] = 1024 + row * 32 + bsc * 8;
  }
  // A: threads 0..127, row tid>>2, stored chunk tid&3
  const bool hasA = tid < 128;
  const int arow = tid >> 2;
  const int alc = ((tid & 3) - (arow >> 1)) & 3;
  const u16* agp = qbase + (size_t)arow * HID + alc * 8;
  const int alo = arow * 32 + (tid & 3) * 8;

  s8v ca;
  s8v cb[8];
  if (hasA) ca = *(const s8v*)agp;
#pragma unroll
  for (int t = 0; t < 8; ++t) cb[t] = *(const s8v*)bgp[t];

  f4v acc[2][8];
#pragma unroll
  for (int i = 0; i < 2; ++i)
#pragma unroll
    for (int j = 0; j < 8; ++j) acc[i][j] = (f4v)0.f;

  for (int ks = 0; ks < 6; ++ks) {
    __syncthreads();
    if (hasA) *(s8v*)&lds[alo] = ca;
#pragma unroll
    for (int t = 0; t < 8; ++t) *(s8v*)&lds[blo[t]] = cb[t];
    __syncthreads();
    if (ks + 1 < 6) {
      const int k0 = (ks + 1) * 32;
      if (hasA) ca = *(const s8v*)(agp + k0);
#pragma unroll
      for (int t = 0; t < 8; ++t) cb[t] = *(const s8v*)(bgp[t] + k0);
    }
    h8v a[2];
#pragma unroll
    for (int i = 0; i < 2; ++i)
      a[i] = *(const h8v*)&lds[(i * 16 + ml) * 32 + fo2];
    h8v bfr[8];
#pragma unroll
    for (int j = 0; j < 8; ++j)
      bfr[j] = *(const h8v*)&lds[1024 + (w * 128 + j * 16 + ml) * 32 + fo2];
#pragma unroll
    for (int i = 0; i < 2; ++i)
#pragma unroll
      for (int j = 0; j < 8; ++j)
        acc[i][j] = __builtin_amdgcn_mfma_f32_16x16x32_f16(a[i], bfr[j], acc[i][j], 0, 0, 0);
  }

  // ---- transform: (s + rel)/sqrt(D) - 0.1*dist ----
#pragma unroll
  for (int i = 0; i < 2; ++i)
#pragma unroll
    for (int j = 0; j < 8; ++j) {
      const int scol = w * 128 + j * 16 + ml;
#pragma unroll
      for (int r = 0; r < 4; ++r) {
        const int srow = bm + i * 16 + quad * 4 + r;
        const float dist = fabsf((float)(srow - scol));
        const float rel = __expf(-0.1f * fminf(dist, 5.0f));
        acc[i][j][r] = (acc[i][j][r] + rel) * INV_SQRT_D - 0.1f * dist;
      }
    }

  // ---- row max: over j, then quad lanes, then 4 waves via LDS ----
  float mx[2][4];
#pragma unroll
  for (int i = 0; i < 2; ++i)
#pragma unroll
    for (int r = 0; r < 4; ++r) {
      float m = acc[i][0][r];
#pragma unroll
      for (int j = 1; j < 8; ++j) m = fmaxf(m, acc[i][j][r]);
#pragma unroll
      for (int o = 1; o < 16; o <<= 1) m = fmaxf(m, __shfl_xor(m, o, 64));
      mx[i][r] = m;
    }
  if (ml == 0) {
#pragma unroll
    for (int i = 0; i < 2; ++i)
#pragma unroll
      for (int r = 0; r < 4; ++r) red[w][i * 16 + quad * 4 + r] = mx[i][r];
  }
  __syncthreads();
#pragma unroll
  for (int i = 0; i < 2; ++i)
#pragma unroll
    for (int r = 0; r < 4; ++r) {
      const int R = i * 16 + quad * 4 + r;
      mx[i][r] = fmaxf(fmaxf(red[0][R], red[1][R]), fmaxf(red[2][R], red[3][R]));
    }
  __syncthreads();

  // ---- exp + row sum ----
  float sm[2][4];
#pragma unroll
  for (int i = 0; i < 2; ++i)
#pragma unroll
    for (int r = 0; r < 4; ++r) {
      float s = 0.f;
#pragma unroll
      for (int j = 0; j < 8; ++j) {
        const float p = __expf(acc[i][j][r] - mx[i][r]);
        acc[i][j][r] = p;
        s += p;
      }
#pragma unroll
      for (int o = 1; o < 16; o <<= 1) s += __shfl_xor(s, o, 64);
      sm[i][r] = s;
    }
  if (ml == 0) {
#pragma unroll
    for (int i = 0; i < 2; ++i)
#pragma unroll
      for (int r = 0; r < 4; ++r) red[w][i * 16 + quad * 4 + r] = sm[i][r];
  }
  __syncthreads();
#pragma unroll
  for (int i = 0; i < 2; ++i)
#pragma unroll
    for (int r = 0; r < 4; ++r) {
      const int R = i * 16 + quad * 4 + r;
      mx[i][r] = 1.0f / (red[0][R] + red[1][R] + red[2][R] + red[3][R]);
    }

  // ---- write fp16 P (ld 512) ----
  u16* Pz = P + (size_t)z * SEQ * SEQ;
#pragma unroll
  for (int i = 0; i < 2; ++i)
#pragma unroll
    for (int r = 0; r < 4; ++r) {
      const int row = bm + i * 16 + quad * 4 + r;
#pragma unroll
      for (int j = 0; j < 8; ++j) {
        const int scol = w * 128 + j * 16 + ml;
        Pz[(size_t)row * SEQ + scol] = f2h(acc[i][j][r] * mx[i][r]);
      }
    }
}

// ---- PV GEMM: 64x192 tile, fp16, paired sub-tiles (BK=64), P ld=512 ----
__global__ __launch_bounds__(256, 3) void pv_mm(
    const u16* __restrict__ P, const u16* __restrict__ vTh, u16* __restrict__ ch)
{
  __shared__ u16 lds[16384];   // sub0: A@0(2048) B@2048(6144); sub1: +8192
  const int z = blockIdx.y, b = z >> 2, hh = z & 3;
  const int bm = blockIdx.x * 64;
  const u16* ah_g = P + (size_t)z * SEQ * SEQ + (size_t)bm * SEQ;       // ld 512
  const u16* bh_g = vTh + (size_t)b * HID * SEQ + (size_t)(hh * 192) * SEQ; // ld 512
  const int tid = threadIdx.x, w = tid >> 6, ln = tid & 63;
  const int srow = ln >> 2;
  const int csw  = ((ln & 3) - (ln >> 3)) & 3;
  const int schunk = csw * 8;
  const int ml = ln & 15, quad = ln >> 4;
  const int fo2 = ((quad + ((ln >> 1) & 3)) & 3) * 8;

  const u16* gp[4];
  int lpo[4];
#pragma unroll
  for (int s = 0; s < 4; ++s) {
    const int p = w * 4 + s;
    if (p < 4) {
      gp[s]  = ah_g + (size_t)(p * 16 + srow) * SEQ + schunk;
      lpo[s] = p * 512 + ln * 8;
    } else {
      const int t = p - 4;
      gp[s]  = bh_g + (size_t)(t * 16 + srow) * SEQ + schunk;
      lpo[s] = 2048 + t * 512 + ln * 8;
    }
  }
  s8v c[8];
#pragma unroll
  for (int s = 0; s < 4; ++s) {
    c[s]     = *(const s8v*)gp[s];
    c[4 + s] = *(const s8v*)(gp[s] + 32);
  }

  f4v acc[12];
#pragma unroll
  for (int j = 0; j < 12; ++j) acc[j] = (f4v)0.f;

  for (int kp = 0; kp < 8; ++kp) {
    __syncthreads();
#pragma unroll
    for (int s = 0; s < 4; ++s) {
      *(s8v*)&lds[lpo[s]]        = c[s];
      *(s8v*)&lds[8192 + lpo[s]] = c[4 + s];
    }
    __syncthreads();
    if (kp + 1 < 8) {
      const int k0 = (kp + 1) * 64;
#pragma unroll
      for (int s = 0; s < 4; ++s) {
        c[s]     = *(const s8v*)(gp[s] + k0);
        c[4 + s] = *(const s8v*)(gp[s] + k0 + 32);
      }
    }
#pragma unroll
    for (int sub = 0; sub < 2; ++sub) {
      const int so = sub * 8192;
      const h8v a = *(const h8v*)&lds[so + (w * 16 + ml) * 32 + fo2];
      h8v bfrag[12];
#pragma unroll
      for (int j = 0; j < 12; ++j)
        bfrag[j] = *(const h8v*)&lds[so + 2048 + (j * 16 + ml) * 32 + fo2];
#pragma unroll
      for (int j = 0; j < 12; ++j)
        acc[j] = __builtin_amdgcn_mfma_f32_16x16x32_f16(a, bfrag[j], acc[j], 0, 0, 0);
    }
  }
#pragma unroll
  for (int j = 0; j < 12; ++j) {
    const int gcol = hh * 192 + j * 16 + ml;
#pragma unroll
    for (int r = 0; r < 4; ++r) {
      const int m = bm + w * 16 + quad * 4 + r;
      const size_t idx = (size_t)(b * SEQ + m) * HID + gcol;
      ch[idx] = f2h(acc[j][r]);
    }
  }
}

// ---- projection GEMM + bias + residual -> h fp32 (XCD-swizzled, fp16) ----
__global__ __launch_bounds__(256, 3) void proj_mm(
    const u16* __restrict__ ch, const u16* __restrict__ WTh,
    const float* __restrict__ bo, const float* __restrict__ x, float* __restrict__ h)
{
  __shared__ u16 lds[16384];
  const int id = blockIdx.x;
  const int xcd = id & 7;
  const int s = id >> 3;            // 0..47
  const int bx = s % 6;
  const int yl = s / 6;             // 0..7
  const int bm = (yl * 8 + xcd) * 128;
  const int bn = bx * 128;
  const size_t wtoff = (size_t)3 * HID * HID + (size_t)bn * HID;
  f4v acc[4][4];
#pragma unroll
  for (int i = 0; i < 4; ++i)
#pragma unroll
    for (int j = 0; j < 4; ++j) acc[i][j] = (f4v)0.f;
  mm_core128<24>(ch + (size_t)bm * HID, HID, WTh + wtoff, HID, lds, acc);
  const int tid = threadIdx.x, w = tid >> 6, ln = tid & 63;
  const int ml = ln & 15, quad = ln >> 4;
  const int wr = (w >> 1) * 64, wc = (w & 1) * 64;
#pragma unroll
  for (int i = 0; i < 4; ++i)
#pragma unroll
    for (int j = 0; j < 4; ++j) {
      const int gcol = bn + wc + j * 16 + ml;
      const float bv_ = bo[gcol];
#pragma unroll
      for (int r = 0; r < 4; ++r) {
        const int grow = bm + wr + i * 16 + quad * 4 + r;
        const size_t idx = (size_t)grow * HID + gcol;
        h[idx] = acc[i][j][r] + bv_ + x[idx];
      }
    }
}

// ---- LayerNorm + 9-label classifier ----
__global__ __launch_bounds__(256) void ln_logits_kernel(
    const float* __restrict__ h, const float* __restrict__ g,
    const float* __restrict__ bta, const float* __restrict__ Ws,
    const float* __restrict__ bsv, float* __restrict__ span)
{
  const int row = blockIdx.x;
  const int tid = threadIdx.x;
  const float* hr = h + (size_t)row * HID;
  const float x0 = hr[tid], x1 = hr[tid + 256], x2 = hr[tid + 512];
  float s = x0 + x1 + x2;
  float sq = x0 * x0 + x1 * x1 + x2 * x2;
#pragma unroll
  for (int o = 32; o > 0; o >>= 1) { s += __shfl_down(s, o, 64); sq += __shfl_down(sq, o, 64); }
  __shared__ float red[8];
  __shared__ float smu, srs;
  const int wid = tid >> 6, lid = tid & 63;
  if (lid == 0) { red[wid] = s; red[4 + wid] = sq; }
  __syncthreads();
  if (tid == 0) {
    const float ts = red[0] + red[1] + red[2] + red[3];
    const float tq = red[4] + red[5] + red[6] + red[7];
    const float mu = ts / 768.0f;
    const float var = tq / 768.0f - mu * mu;
    smu = mu; srs = rsqrtf(var + 1e-5f);
  }
  __syncthreads();
  const float mu = smu, rs = srs;
  const float n0 = (x0 - mu) * rs * g[tid] + bta[tid];
  const float n1 = (x1 - mu) * rs * g[tid + 256] + bta[tid + 256];
  const float n2 = (x2 - mu) * rs * g[tid + 512] + bta[tid + 512];
  float pl[9];
#pragma unroll
  for (int l = 0; l < 9; ++l)
    pl[l] = n0 * Ws[(size_t)tid * 9 + l]
          + n1 * Ws[(size_t)(tid + 256) * 9 + l]
          + n2 * Ws[(size_t)(tid + 512) * 9 + l];
#pragma unroll
  for (int l = 0; l < 9; ++l)
#pragma unroll
    for (int o = 32; o > 0; o >>= 1) pl[l] += __shfl_down(pl[l], o, 64);
  __shared__ float lred[4][9];
  if (lid == 0) {
#pragma unroll
    for (int l = 0; l < 9; ++l) lred[wid][l] = pl[l];
  }
  __syncthreads();
  if (tid < 9) {
    span[(size_t)row * 9 + tid] =
        lred[0][tid] + lred[1][tid] + lred[2][tid] + lred[3][tid] + bsv[tid];
  }
}

// ---- entity-bias bump ----
__global__ __launch_bounds__(256) void bump_kernel(
    const float* __restrict__ span, const float* __restrict__ eb, float* __restrict__ out)
{
  const int idx = blockIdx.x * 256 + threadIdx.x;
  if (idx >= ROWS) return;
  const int j = idx & (SEQ - 1);
  const float* sl = span + (size_t)idx * 9;
  float v[9];
#pragma unroll
  for (int l = 0; l < 9; ++l) v[l] = sl[l];
  if (j >= 1) {
    const float* sp = sl - 9;
    float m = sp[0]; int am = 0;
#pragma unroll
    for (int l = 1; l < 9; ++l) { const float t = sp[l]; if (t > m) { m = t; am = l; } }
    if (am == 1) v[2] += 2.0f * eb[2];
  }
#pragma unroll
  for (int l = 0; l < 9; ++l) out[(size_t)idx * 9 + l] = v[l];
}

extern "C" void kernel_launch(void* const* d_in, const int* in_sizes, int n_in,
                              void* d_out, int out_size, void* d_ws, size_t ws_size,
                              hipStream_t stream)
{
  (void)in_sizes; (void)n_in; (void)out_size; (void)ws_size;
  const float* x   = (const float*)d_in[0];
  const float* Wq  = (const float*)d_in[1];
  const float* bq  = (const float*)d_in[2];
  const float* Wk  = (const float*)d_in[3];
  const float* bk  = (const float*)d_in[4];
  const float* Wv  = (const float*)d_in[5];
  const float* bv  = (const float*)d_in[6];
  const float* Wo  = (const float*)d_in[7];
  const float* bo  = (const float*)d_in[8];
  const float* lng = (const float*)d_in[9];
  const float* lnb = (const float*)d_in[10];
  const float* Ws  = (const float*)d_in[11];
  const float* bs  = (const float*)d_in[12];
  const float* eb  = (const float*)d_in[13];
  float* out = (float*)d_out;

  char* ws = (char*)d_ws;
  u16* xh  = (u16*)(ws + 0);                       // fp16 x (12.6MB)
  u16* vTh = xh;                                   // reuse after qkv
  u16* WTh = (u16*)(ws + 25165824);                // fp16 WT (4 matrices)
  u16* qh  = (u16*)(ws + 34603008);
  u16* kh  = (u16*)(ws + 59768832);
  u16* vtmp16 = (u16*)(ws + 84934656);             // fp16 v (12.6MB)
  float* hb = (float*)(ws + 84934656);             // fp32 h (25MB, after vtrans)
  u16* Pb  = (u16*)(ws + 117440512);               // fp16 probs (33.5MB)
  float* spanb = (float*)(ws + 152043520);
  u16* ctxh = qh;                                  // q dead after scores

  splitx<<<dim3(1572864 / 256), 256, 0, stream>>>(x, xh);
  wsplit<<<dim3(24, 24, 4), 256, 0, stream>>>(Wq, Wk, Wv, Wo, WTh);
  qkv_mm<<<dim3(1152), 256, 0, stream>>>(xh, WTh, bq, bk, bv, qh, kh, vtmp16);
  vtrans<<<dim3(24, 16, 16), 256, 0, stream>>>(vtmp16, vTh);
  scores_softmax<<<dim3(16, 64), 256, 0, stream>>>(qh, kh, Pb);
  pv_mm<<<dim3(8, 64), 256, 0, stream>>>(Pb, vTh, ctxh);
  proj_mm<<<dim3(384), 256, 0, stream>>>(ctxh, WTh, bo, x, hb);
  ln_logits_kernel<<<dim3(ROWS), 256, 0, stream>>>(hb, lng, lnb, Ws, bs, spanb);
  bump_kernel<<<dim3(ROWS / 256), 256, 0, stream>>>(spanb, eb, out);
}

// Round 12
// 234.398 us; speedup vs baseline: 2.5657x; 1.0437x over previous
//
#include <hip/hip_runtime.h>
#include <math.h>

#define SEQ 512
#define HID 768
#define NBATCH 16
#define ROWS 8192
#define INV_SQRT_D 0.07216878364870323f

typedef short s8v __attribute__((ext_vector_type(8)));
typedef _Float16 h8v __attribute__((ext_vector_type(8)));
typedef float f4v __attribute__((ext_vector_type(4)));
typedef unsigned short u16;

// ---- fp16 helper (RNE) ----
__device__ __forceinline__ u16 f2h(float f) {
  _Float16 h = (_Float16)f;
  return __builtin_bit_cast(u16, h);
}

// ---------------------------------------------------------------------------
// fp16 GEMM core (R10): BK=64 via paired 32-wide sub-tiles, one barrier-pair
// per 64 K. LDS 32KB: sub0 {A@0,B@4096}, sub1 {A@8192,B@12288} (u16 idx).
// Swizzle (row,chunk)->row*32+((chunk+(row>>1))&3)*8: conflict-free b128 reads.
// ---------------------------------------------------------------------------
template <int KSTEPS>   // number of 32-wide steps; must be even
__device__ __forceinline__ void mm_core128(
    const u16* __restrict__ A, const int lda,
    const u16* __restrict__ B, const int ldb,
    u16* lds, f4v (&acc)[4][4])
{
  const int tid = threadIdx.x;
  const int w = tid >> 6, ln = tid & 63;
  const u16* src = (w >> 1) ? B : A;
  const int ld = (w >> 1) ? ldb : lda;
  const int half = w & 1;
  const int srow = ln >> 2;
  const int csw  = ((ln & 3) - (ln >> 3)) & 3;
  const int ml = ln & 15, quad = ln >> 4;
  const int fo2 = ((quad + ((ln >> 1) & 3)) & 3) * 8;
  const int wr = (w >> 1) * 64, wc = (w & 1) * 64;

  const u16* gp[4];
  int lpo[4];
#pragma unroll
  for (int t = 0; t < 4; ++t) {
    const int row = half * 64 + t * 16 + srow;
    gp[t]  = src + (size_t)row * ld + csw * 8;
    lpo[t] = (w >> 1) * 4096 + half * 2048 + t * 512 + ln * 8;
  }
  s8v c[8];
#pragma unroll
  for (int t = 0; t < 4; ++t) {
    c[t]     = *(const s8v*)gp[t];
    c[4 + t] = *(const s8v*)(gp[t] + 32);
  }

  for (int kp = 0; kp < KSTEPS / 2; ++kp) {
    __syncthreads();
#pragma unroll
    for (int t = 0; t < 4; ++t) {
      *(s8v*)&lds[lpo[t]]        = c[t];
      *(s8v*)&lds[8192 + lpo[t]] = c[4 + t];
    }
    __syncthreads();
    if (kp + 1 < KSTEPS / 2) {
      const int k0 = (kp + 1) * 64;
#pragma unroll
      for (int t = 0; t < 4; ++t) {
        c[t]     = *(const s8v*)(gp[t] + k0);
        c[4 + t] = *(const s8v*)(gp[t] + k0 + 32);
      }
    }
#pragma unroll
    for (int sub = 0; sub < 2; ++sub) {
      const int so = sub * 8192;
      h8v a[4], b[4];
#pragma unroll
      for (int i = 0; i < 4; ++i)
        a[i] = *(const h8v*)&lds[so + (wr + i * 16 + ml) * 32 + fo2];
#pragma unroll
      for (int j = 0; j < 4; ++j)
        b[j] = *(const h8v*)&lds[so + 4096 + (wc + j * 16 + ml) * 32 + fo2];
#pragma unroll
      for (int i = 0; i < 4; ++i)
#pragma unroll
        for (int j = 0; j < 4; ++j)
          acc[i][j] = __builtin_amdgcn_mfma_f32_16x16x32_f16(a[i], b[j], acc[i][j], 0, 0, 0);
    }
  }
}

// ---- prep: x -> fp16 ----
__global__ __launch_bounds__(256) void splitx(const float* __restrict__ x,
                                              u16* __restrict__ xh)
{
  const int i = blockIdx.x * 256 + threadIdx.x;
  const float4 v = ((const float4*)x)[i];
  ((ushort4*)xh)[i] = make_ushort4(f2h(v.x), f2h(v.y), f2h(v.z), f2h(v.w));
}

// ---- prep: transpose weights: WT[z][n][k] = W_z[k][n], fp16 ----
__global__ __launch_bounds__(256) void wsplit(
    const float* __restrict__ Wq, const float* __restrict__ Wk,
    const float* __restrict__ Wv, const float* __restrict__ Wo,
    u16* __restrict__ WTh)
{
  __shared__ float t[32][33];
  const int z = blockIdx.z;
  const float* W = (z == 0) ? Wq : (z == 1) ? Wk : (z == 2) ? Wv : Wo;
  const int n0 = blockIdx.x * 32, k0 = blockIdx.y * 32;
  const int tx = threadIdx.x & 31, ty = threadIdx.x >> 5;
#pragma unroll
  for (int i = 0; i < 4; ++i)
    t[ty + 8 * i][tx] = W[(size_t)(k0 + ty + 8 * i) * HID + n0 + tx];
  __syncthreads();
#pragma unroll
  for (int i = 0; i < 4; ++i) {
    const float v = t[tx][ty + 8 * i];
    const size_t idx = (size_t)z * HID * HID + (size_t)(n0 + ty + 8 * i) * HID + k0 + tx;
    WTh[idx] = f2h(v);
  }
}

// ---- QKV GEMM, XCD-swizzled 1D grid (1152 blocks), fp16 BK=64 core ----
__global__ __launch_bounds__(256, 3) void qkv_mm(
    const u16* __restrict__ xh, const u16* __restrict__ WTh,
    const float* __restrict__ bq, const float* __restrict__ bk, const float* __restrict__ bv,
    u16* __restrict__ qh, u16* __restrict__ kh, u16* __restrict__ vtmp16)
{
  __shared__ u16 lds[16384];
  const int id = blockIdx.x;
  const int xcd = id & 7;
  const int s = id >> 3;            // 0..143
  const int bx = s % 6;
  const int yl = (s / 6) & 7;
  const int z  = s / 48;
  const int bm = (yl * 8 + xcd) * 128;
  const int bn = bx * 128;
  const size_t wtoff = (size_t)z * HID * HID + (size_t)bn * HID;
  f4v acc[4][4];
#pragma unroll
  for (int i = 0; i < 4; ++i)
#pragma unroll
    for (int j = 0; j < 4; ++j) acc[i][j] = (f4v)0.f;
  mm_core128<24>(xh + (size_t)bm * HID, HID, WTh + wtoff, HID, lds, acc);
  const int tid = threadIdx.x, w = tid >> 6, ln = tid & 63;
  const int ml = ln & 15, quad = ln >> 4;
  const int wr = (w >> 1) * 64, wc = (w & 1) * 64;
  const float* bias = (z == 0) ? bq : (z == 1) ? bk : bv;
#pragma unroll
  for (int i = 0; i < 4; ++i)
#pragma unroll
    for (int j = 0; j < 4; ++j) {
      const int gcol = bn + wc + j * 16 + ml;
      const float bv_ = bias[gcol];
#pragma unroll
      for (int r = 0; r < 4; ++r) {
        const int grow = bm + wr + i * 16 + quad * 4 + r;
        const float v = acc[i][j][r] + bv_;
        const size_t idx = (size_t)grow * HID + gcol;
        if (z == 2)      vtmp16[idx] = f2h(v);
        else if (z == 0) qh[idx] = f2h(v);
        else             kh[idx] = f2h(v);
      }
    }
}

// ---- prep: transpose v (fp16 passthrough): vT[b][n][c] = vtmp16[b][c][n] ----
__global__ __launch_bounds__(256) void vtrans(const u16* __restrict__ vtmp16,
                                              u16* __restrict__ vTh)
{
  __shared__ u16 t[32][33];
  const int b = blockIdx.z, n0 = blockIdx.x * 32, c0 = blockIdx.y * 32;
  const int tx = threadIdx.x & 31, ty = threadIdx.x >> 5;
  const u16* src = vtmp16 + (size_t)b * SEQ * HID;
#pragma unroll
  for (int i = 0; i < 4; ++i)
    t[ty + 8 * i][tx] = src[(size_t)(c0 + ty + 8 * i) * HID + n0 + tx];
  __syncthreads();
#pragma unroll
  for (int i = 0; i < 4; ++i) {
    const size_t idx = (size_t)b * HID * SEQ + (size_t)(n0 + ty + 8 * i) * SEQ + c0 + tx;
    vTh[idx] = t[tx][ty + 8 * i];
  }
}

// ---------------------------------------------------------------------------
// FLASH-FUSED attention: block = 32 Q-rows x full 512 K-cols for one (b,head).
// Phase 1 (R11 scores_softmax): QK^T in 6 BK=32 steps -> rel-bias/scale/mask
// -> in-register row softmax (quad shfl + 4-wave LDS reduce).
// Phase 2: write fp16 P tile (32x512) into LDS, swizzled (stored chunk =
// (logical+(row>>1))&3) so phase-3 A-frag b128 reads are 2-way/free.
// Phase 3: PV K-loop, 16 BK=32 steps: stage vT tile (192x32, 3 s8v/thread),
// A-frags straight from LDS-resident P -> 6 MFMA/wave-kstep -> ctx fp16.
// LDS: phase1 A@0(1024) B@1024(16384); phase3 P@0(16384) vT@16384(6144).
// ---------------------------------------------------------------------------
__global__ __launch_bounds__(256, 2) void attn_fused(
    const u16* __restrict__ qh, const u16* __restrict__ kh,
    const u16* __restrict__ vTh, u16* __restrict__ ch)
{
  __shared__ u16 lds[22528];
  __shared__ float red[4][32];
  const int z = blockIdx.y, b = z >> 2, hh = z & 3;
  const int bm = blockIdx.x * 32;
  const int tid = threadIdx.x, w = tid >> 6, ln = tid & 63;
  const int ml = ln & 15, quad = ln >> 4;
  const int fo2 = ((quad + ((ml >> 1) & 3)) & 3) * 8;
  const u16* qbase = qh + (size_t)(b * SEQ + bm) * HID + hh * 192;
  const u16* kbase = kh + (size_t)(b * SEQ) * HID + hh * 192;

  // phase-1 staging: B: 8 chunks/thread; A: threads 0..127
  const int brow0 = tid >> 2, bsc = tid & 3;
  const u16* bgp[8];
  int blo[8];
#pragma unroll
  for (int t = 0; t < 8; ++t) {
    const int row = t * 64 + brow0;
    const int lc = (bsc - (row >> 1)) & 3;
    bgp[t] = kbase + (size_t)row * HID + lc * 8;
    blo[t] = 1024 + row * 32 + bsc * 8;
  }
  const bool hasA = tid < 128;
  const int arow = tid >> 2;
  const int alc = ((tid & 3) - (arow >> 1)) & 3;
  const u16* agp = qbase + (size_t)arow * HID + alc * 8;
  const int alo = arow * 32 + (tid & 3) * 8;

  s8v ca;
  s8v cb[8];
  if (hasA) ca = *(const s8v*)agp;
#pragma unroll
  for (int t = 0; t < 8; ++t) cb[t] = *(const s8v*)bgp[t];

  f4v acc[2][8];
#pragma unroll
  for (int i = 0; i < 2; ++i)
#pragma unroll
    for (int j = 0; j < 8; ++j) acc[i][j] = (f4v)0.f;

  for (int ks = 0; ks < 6; ++ks) {
    __syncthreads();
    if (hasA) *(s8v*)&lds[alo] = ca;
#pragma unroll
    for (int t = 0; t < 8; ++t) *(s8v*)&lds[blo[t]] = cb[t];
    __syncthreads();
    if (ks + 1 < 6) {
      const int k0 = (ks + 1) * 32;
      if (hasA) ca = *(const s8v*)(agp + k0);
#pragma unroll
      for (int t = 0; t < 8; ++t) cb[t] = *(const s8v*)(bgp[t] + k0);
    }
    h8v a[2];
#pragma unroll
    for (int i = 0; i < 2; ++i)
      a[i] = *(const h8v*)&lds[(i * 16 + ml) * 32 + fo2];
    h8v bfr[8];
#pragma unroll
    for (int j = 0; j < 8; ++j)
      bfr[j] = *(const h8v*)&lds[1024 + (w * 128 + j * 16 + ml) * 32 + fo2];
#pragma unroll
    for (int i = 0; i < 2; ++i)
#pragma unroll
      for (int j = 0; j < 8; ++j)
        acc[i][j] = __builtin_amdgcn_mfma_f32_16x16x32_f16(a[i], bfr[j], acc[i][j], 0, 0, 0);
  }

  // ---- transform: (s + rel)/sqrt(D) - 0.1*dist ----
#pragma unroll
  for (int i = 0; i < 2; ++i)
#pragma unroll
    for (int j = 0; j < 8; ++j) {
      const int scol = w * 128 + j * 16 + ml;
#pragma unroll
      for (int r = 0; r < 4; ++r) {
        const int srow = bm + i * 16 + quad * 4 + r;
        const float dist = fabsf((float)(srow - scol));
        const float rel = __expf(-0.1f * fminf(dist, 5.0f));
        acc[i][j][r] = (acc[i][j][r] + rel) * INV_SQRT_D - 0.1f * dist;
      }
    }

  // ---- row max ----
  float mx[2][4];
#pragma unroll
  for (int i = 0; i < 2; ++i)
#pragma unroll
    for (int r = 0; r < 4; ++r) {
      float m = acc[i][0][r];
#pragma unroll
      for (int j = 1; j < 8; ++j) m = fmaxf(m, acc[i][j][r]);
#pragma unroll
      for (int o = 1; o < 16; o <<= 1) m = fmaxf(m, __shfl_xor(m, o, 64));
      mx[i][r] = m;
    }
  if (ml == 0) {
#pragma unroll
    for (int i = 0; i < 2; ++i)
#pragma unroll
      for (int r = 0; r < 4; ++r) red[w][i * 16 + quad * 4 + r] = mx[i][r];
  }
  __syncthreads();
#pragma unroll
  for (int i = 0; i < 2; ++i)
#pragma unroll
    for (int r = 0; r < 4; ++r) {
      const int R = i * 16 + quad * 4 + r;
      mx[i][r] = fmaxf(fmaxf(red[0][R], red[1][R]), fmaxf(red[2][R], red[3][R]));
    }
  __syncthreads();

  // ---- exp + row sum ----
  float sm[2][4];
#pragma unroll
  for (int i = 0; i < 2; ++i)
#pragma unroll
    for (int r = 0; r < 4; ++r) {
      float s = 0.f;
#pragma unroll
      for (int j = 0; j < 8; ++j) {
        const float p = __expf(acc[i][j][r] - mx[i][r]);
        acc[i][j][r] = p;
        s += p;
      }
#pragma unroll
      for (int o = 1; o < 16; o <<= 1) s += __shfl_xor(s, o, 64);
      sm[i][r] = s;
    }
  if (ml == 0) {
#pragma unroll
    for (int i = 0; i < 2; ++i)
#pragma unroll
      for (int r = 0; r < 4; ++r) red[w][i * 16 + quad * 4 + r] = sm[i][r];
  }
  __syncthreads();
#pragma unroll
  for (int i = 0; i < 2; ++i)
#pragma unroll
    for (int r = 0; r < 4; ++r) {
      const int R = i * 16 + quad * 4 + r;
      mx[i][r] = 1.0f / (red[0][R] + red[1][R] + red[2][R] + red[3][R]);
    }
  __syncthreads();   // all waves past phase-1 LDS reads; safe to overwrite with P

  // ---- phase 2: write fp16 P (32x512) into LDS, swizzled ----
#pragma unroll
  for (int i = 0; i < 2; ++i)
#pragma unroll
    for (int r = 0; r < 4; ++r) {
      const int row = i * 16 + quad * 4 + r;       // local 0..31
      const int rsw = (row >> 1) & 3;
      const int rbase = row * 512;
#pragma unroll
      for (int j = 0; j < 8; ++j) {
        const int col = w * 128 + j * 16 + ml;
        const int addr = rbase + (col & ~31) + ((((col >> 3) & 3) + rsw) & 3) * 8 + (col & 7);
        lds[addr] = f2h(acc[i][j][r] * mx[i][r]);
      }
    }

  // ---- phase 3: PV K-loop, vT tile staged at lds+16384 ----
  const u16* vbase = vTh + (size_t)b * HID * SEQ + (size_t)(hh * 192) * SEQ;
  const u16* vgp[3];
  int vlo[3];
#pragma unroll
  for (int t = 0; t < 3; ++t) {
    const int cch = t * 256 + tid;                 // 0..767
    const int vrow = cch >> 2, vsc = cch & 3;
    const int vlc = (vsc - (vrow >> 1)) & 3;
    vgp[t] = vbase + (size_t)vrow * SEQ + vlc * 8;
    vlo[t] = 16384 + cch * 8;
  }
  s8v vc[3];
#pragma unroll
  for (int t = 0; t < 3; ++t) vc[t] = *(const s8v*)vgp[t];

  f4v acc2[2][3];
#pragma unroll
  for (int i = 0; i < 2; ++i)
#pragma unroll
    for (int j = 0; j < 3; ++j) acc2[i][j] = (f4v)0.f;

  for (int ks = 0; ks < 16; ++ks) {
    __syncthreads();
#pragma unroll
    for (int t = 0; t < 3; ++t) *(s8v*)&lds[vlo[t]] = vc[t];
    __syncthreads();
    if (ks + 1 < 16) {
      const int k0 = (ks + 1) * 32;
#pragma unroll
      for (int t = 0; t < 3; ++t) vc[t] = *(const s8v*)(vgp[t] + k0);
    }
    h8v a2[2];
#pragma unroll
    for (int i = 0; i < 2; ++i)
      a2[i] = *(const h8v*)&lds[(i * 16 + ml) * 512 + ks * 32 + fo2];
    h8v b2[3];
#pragma unroll
    for (int j = 0; j < 3; ++j)
      b2[j] = *(const h8v*)&lds[16384 + (w * 48 + j * 16 + ml) * 32 + fo2];
#pragma unroll
    for (int i = 0; i < 2; ++i)
#pragma unroll
      for (int j = 0; j < 3; ++j)
        acc2[i][j] = __builtin_amdgcn_mfma_f32_16x16x32_f16(a2[i], b2[j], acc2[i][j], 0, 0, 0);
  }

  // ---- ctx out: rows bm..bm+31, cols hh*192 + w*48 + j*16 + ml ----
#pragma unroll
  for (int i = 0; i < 2; ++i)
#pragma unroll
    for (int j = 0; j < 3; ++j) {
      const int gcol = hh * 192 + w * 48 + j * 16 + ml;
#pragma unroll
      for (int r = 0; r < 4; ++r) {
        const int m = bm + i * 16 + quad * 4 + r;
        ch[(size_t)(b * SEQ + m) * HID + gcol] = f2h(acc2[i][j][r]);
      }
    }
}

// ---- projection GEMM + bias + residual -> h fp32 (XCD-swizzled, fp16) ----
__global__ __launch_bounds__(256, 3) void proj_mm(
    const u16* __restrict__ ch, const u16* __restrict__ WTh,
    const float* __restrict__ bo, const float* __restrict__ x, float* __restrict__ h)
{
  __shared__ u16 lds[16384];
  const int id = blockIdx.x;
  const int xcd = id & 7;
  const int s = id >> 3;            // 0..47
  const int bx = s % 6;
  const int yl = s / 6;             // 0..7
  const int bm = (yl * 8 + xcd) * 128;
  const int bn = bx * 128;
  const size_t wtoff = (size_t)3 * HID * HID + (size_t)bn * HID;
  f4v acc[4][4];
#pragma unroll
  for (int i = 0; i < 4; ++i)
#pragma unroll
    for (int j = 0; j < 4; ++j) acc[i][j] = (f4v)0.f;
  mm_core128<24>(ch + (size_t)bm * HID, HID, WTh + wtoff, HID, lds, acc);
  const int tid = threadIdx.x, w = tid >> 6, ln = tid & 63;
  const int ml = ln & 15, quad = ln >> 4;
  const int wr = (w >> 1) * 64, wc = (w & 1) * 64;
#pragma unroll
  for (int i = 0; i < 4; ++i)
#pragma unroll
    for (int j = 0; j < 4; ++j) {
      const int gcol = bn + wc + j * 16 + ml;
      const float bv_ = bo[gcol];
#pragma unroll
      for (int r = 0; r < 4; ++r) {
        const int grow = bm + wr + i * 16 + quad * 4 + r;
        const size_t idx = (size_t)grow * HID + gcol;
        h[idx] = acc[i][j][r] + bv_ + x[idx];
      }
    }
}

// ---- LayerNorm + 9-label classifier ----
__global__ __launch_bounds__(256) void ln_logits_kernel(
    const float* __restrict__ h, const float* __restrict__ g,
    const float* __restrict__ bta, const float* __restrict__ Ws,
    const float* __restrict__ bsv, float* __restrict__ span)
{
  const int row = blockIdx.x;
  const int tid = threadIdx.x;
  const float* hr = h + (size_t)row * HID;
  const float x0 = hr[tid], x1 = hr[tid + 256], x2 = hr[tid + 512];
  float s = x0 + x1 + x2;
  float sq = x0 * x0 + x1 * x1 + x2 * x2;
#pragma unroll
  for (int o = 32; o > 0; o >>= 1) { s += __shfl_down(s, o, 64); sq += __shfl_down(sq, o, 64); }
  __shared__ float red[8];
  __shared__ float smu, srs;
  const int wid = tid >> 6, lid = tid & 63;
  if (lid == 0) { red[wid] = s; red[4 + wid] = sq; }
  __syncthreads();
  if (tid == 0) {
    const float ts = red[0] + red[1] + red[2] + red[3];
    const float tq = red[4] + red[5] + red[6] + red[7];
    const float mu = ts / 768.0f;
    const float var = tq / 768.0f - mu * mu;
    smu = mu; srs = rsqrtf(var + 1e-5f);
  }
  __syncthreads();
  const float mu = smu, rs = srs;
  const float n0 = (x0 - mu) * rs * g[tid] + bta[tid];
  const float n1 = (x1 - mu) * rs * g[tid + 256] + bta[tid + 256];
  const float n2 = (x2 - mu) * rs * g[tid + 512] + bta[tid + 512];
  float pl[9];
#pragma unroll
  for (int l = 0; l < 9; ++l)
    pl[l] = n0 * Ws[(size_t)tid * 9 + l]
          + n1 * Ws[(size_t)(tid + 256) * 9 + l]
          + n2 * Ws[(size_t)(tid + 512) * 9 + l];
#pragma unroll
  for (int l = 0; l < 9; ++l)
#pragma unroll
    for (int o = 32; o > 0; o >>= 1) pl[l] += __shfl_down(pl[l], o, 64);
  __shared__ float lred[4][9];
  if (lid == 0) {
#pragma unroll
    for (int l = 0; l < 9; ++l) lred[wid][l] = pl[l];
  }
  __syncthreads();
  if (tid < 9) {
    span[(size_t)row * 9 + tid] =
        lred[0][tid] + lred[1][tid] + lred[2][tid] + lred[3][tid] + bsv[tid];
  }
}

// ---- entity-bias bump ----
__global__ __launch_bounds__(256) void bump_kernel(
    const float* __restrict__ span, const float* __restrict__ eb, float* __restrict__ out)
{
  const int idx = blockIdx.x * 256 + threadIdx.x;
  if (idx >= ROWS) return;
  const int j = idx & (SEQ - 1);
  const float* sl = span + (size_t)idx * 9;
  float v[9];
#pragma unroll
  for (int l = 0; l < 9; ++l) v[l] = sl[l];
  if (j >= 1) {
    const float* sp = sl - 9;
    float m = sp[0]; int am = 0;
#pragma unroll
    for (int l = 1; l < 9; ++l) { const float t = sp[l]; if (t > m) { m = t; am = l; } }
    if (am == 1) v[2] += 2.0f * eb[2];
  }
#pragma unroll
  for (int l = 0; l < 9; ++l) out[(size_t)idx * 9 + l] = v[l];
}

extern "C" void kernel_launch(void* const* d_in, const int* in_sizes, int n_in,
                              void* d_out, int out_size, void* d_ws, size_t ws_size,
                              hipStream_t stream)
{
  (void)in_sizes; (void)n_in; (void)out_size; (void)ws_size;
  const float* x   = (const float*)d_in[0];
  const float* Wq  = (const float*)d_in[1];
  const float* bq  = (const float*)d_in[2];
  const float* Wk  = (const float*)d_in[3];
  const float* bk  = (const float*)d_in[4];
  const float* Wv  = (const float*)d_in[5];
  const float* bv  = (const float*)d_in[6];
  const float* Wo  = (const float*)d_in[7];
  const float* bo  = (const float*)d_in[8];
  const float* lng = (const float*)d_in[9];
  const float* lnb = (const float*)d_in[10];
  const float* Ws  = (const float*)d_in[11];
  const float* bs  = (const float*)d_in[12];
  const float* eb  = (const float*)d_in[13];
  float* out = (float*)d_out;

  char* ws = (char*)d_ws;
  u16* xh  = (u16*)(ws + 0);                       // fp16 x (12.6MB)
  u16* vTh = xh;                                   // reuse after qkv
  u16* WTh = (u16*)(ws + 25165824);                // fp16 WT (4 matrices)
  u16* qh  = (u16*)(ws + 34603008);
  u16* kh  = (u16*)(ws + 59768832);
  u16* vtmp16 = (u16*)(ws + 84934656);             // fp16 v (12.6MB)
  float* hb = (float*)(ws + 84934656);             // fp32 h (25MB, after vtrans)
  float* spanb = (float*)(ws + 152043520);
  u16* ctxh = qh;                                  // q dead after attn

  splitx<<<dim3(1572864 / 256), 256, 0, stream>>>(x, xh);
  wsplit<<<dim3(24, 24, 4), 256, 0, stream>>>(Wq, Wk, Wv, Wo, WTh);
  qkv_mm<<<dim3(1152), 256, 0, stream>>>(xh, WTh, bq, bk, bv, qh, kh, vtmp16);
  vtrans<<<dim3(24, 16, 16), 256, 0, stream>>>(vtmp16, vTh);
  attn_fused<<<dim3(16, 64), 256, 0, stream>>>(qh, kh, vTh, ctxh);
  proj_mm<<<dim3(384), 256, 0, stream>>>(ctxh, WTh, bo, x, hb);
  ln_logits_kernel<<<dim3(ROWS), 256, 0, stream>>>(hb, lng, lnb, Ws, bs, spanb);
  bump_kernel<<<dim3(ROWS / 256), 256, 0, stream>>>(spanb, eb, out);
}